// Round 3
// baseline (2991.270 us; speedup 1.0000x reference)
//
#include <hip/hip_runtime.h>
#include <hip/hip_bf16.h>

typedef __hip_bfloat16 bf16;

#define HW 1024

// ---------- helpers ----------
__device__ __forceinline__ float dsilu(float x){ return x / (1.f + __expf(-x)); }

// ---------- generic 1x1 conv (fp32 in, fp32 out) ----------
// MODE 0: BN+SiLU. MODE 1: qkv (q *= 0.125, k += rw+rh, raw). MODE 2: BN+SiLU + residual add.
// grid = (Cout, B), block = 256, each thread does 4 consecutive pixels.
template<int MODE>
__global__ __launch_bounds__(256)
void conv1x1_k(const float* __restrict__ in, long in_bs, int Cin,
               const float* __restrict__ w, const float* __restrict__ bnp,
               const float* __restrict__ res, long res_bs,
               const float* __restrict__ rw, const float* __restrict__ rh,
               float* __restrict__ out, long out_bs)
{
  const int co = blockIdx.x, b = blockIdx.y, Cout = gridDim.x;
  const int tid = threadIdx.x;
  __shared__ float wrow[1024];
  for (int i = tid; i < Cin; i += 256) wrow[i] = w[(long)co*Cin + i];
  __syncthreads();
  const int p0 = tid * 4;
  float a0 = 0.f, a1 = 0.f, a2 = 0.f, a3 = 0.f;
  const float* inb = in + (long)b*in_bs + p0;
#pragma unroll 4
  for (int ci = 0; ci < Cin; ci++){
    const float wv = wrow[ci];
    const float4 xv = *(const float4*)(inb + (long)ci*HW);
    a0 += wv*xv.x; a1 += wv*xv.y; a2 += wv*xv.z; a3 += wv*xv.w;
  }
  if (MODE == 1){
    if (co < 256){ a0 *= 0.125f; a1 *= 0.125f; a2 *= 0.125f; a3 *= 0.125f; }
    else if (co < 512){
      const int c64 = co - 256;
      const int y = p0 >> 5, x0 = p0 & 31;
      const float rhv = rh[c64*32 + y];
      a0 += rhv + rw[c64*32 + x0    ];
      a1 += rhv + rw[c64*32 + x0 + 1];
      a2 += rhv + rw[c64*32 + x0 + 2];
      a3 += rhv + rw[c64*32 + x0 + 3];
    }
  } else {
    const float g  = bnp[co];
    const float be = bnp[Cout   + co];
    const float mu = bnp[2*Cout + co];
    const float va = bnp[3*Cout + co];
    const float s = g / sqrtf(va + 1e-3f);
    a0 = dsilu((a0 - mu)*s + be);
    a1 = dsilu((a1 - mu)*s + be);
    a2 = dsilu((a2 - mu)*s + be);
    a3 = dsilu((a3 - mu)*s + be);
    if (MODE == 2){
      const float4 rv = *(const float4*)(res + (long)b*res_bs + (long)co*HW + p0);
      a0 += rv.x; a1 += rv.y; a2 += rv.z; a3 += rv.w;
    }
  }
  float4 o; o.x = a0; o.y = a1; o.z = a2; o.w = a3;
  *(float4*)(out + (long)b*out_bs + (long)co*HW + p0) = o;
}

// ---------- zero-pad (8,256,32,32) -> (8,256,34,36) ----------
__global__ __launch_bounds__(256)
void pad_k(const float* __restrict__ in, long in_bs, float* __restrict__ outp)
{
  const int plane = blockIdx.x;              // b*256 + ch
  const int b = plane >> 8, ch = plane & 255;
  const float* src = in + (long)b*in_bs + (long)ch*HW;
  float* dst = outp + (long)plane*1224;      // 34*36
  for (int idx = threadIdx.x; idx < 1224; idx += 256){
    const int r = idx / 36, c = idx - r*36;
    float v = 0.f;
    if (r >= 1 && r <= 32 && c >= 1 && c <= 32) v = src[(r-1)*32 + (c-1)];
    dst[idx] = v;
  }
}

// ---------- 3x3 conv + BN + SiLU on padded input ----------
// grid = (256, B), block = 256, thread does 4 consecutive x of one row.
__global__ __launch_bounds__(256)
void conv3x3_k(const float* __restrict__ inpad, const float* __restrict__ w,
               const float* __restrict__ bnp, float* __restrict__ out)
{
  const int co = blockIdx.x, b = blockIdx.y;
  const int tid = threadIdx.x;
  __shared__ float wf[2304];
  for (int i = tid; i < 2304; i += 256) wf[i] = w[(long)co*2304 + i];
  __syncthreads();
  const int y = tid >> 3, x0 = (tid & 7) << 2;
  float a0 = 0.f, a1 = 0.f, a2 = 0.f, a3 = 0.f;
  const float* base = inpad + (long)b*256*1224 + y*36 + x0;
#pragma unroll 2
  for (int ci = 0; ci < 256; ci++){
    const float* pl = base + (long)ci*1224;
    const float* wc = &wf[ci*9];
#pragma unroll
    for (int r = 0; r < 3; r++){
      const float4 q = *(const float4*)(pl + r*36);
      const float q4 = pl[r*36 + 4];
      const float q5 = pl[r*36 + 5];
      const float w0 = wc[r*3], w1 = wc[r*3+1], w2 = wc[r*3+2];
      a0 += w0*q.x + w1*q.y + w2*q.z;
      a1 += w0*q.y + w1*q.z + w2*q.w;
      a2 += w0*q.z + w1*q.w + w2*q4;
      a3 += w0*q.w + w1*q4  + w2*q5;
    }
  }
  const float g  = bnp[co];
  const float be = bnp[256 + co];
  const float mu = bnp[512 + co];
  const float va = bnp[768 + co];
  const float s = g / sqrtf(va + 1e-3f);
  float4 o;
  o.x = dsilu((a0 - mu)*s + be);
  o.y = dsilu((a1 - mu)*s + be);
  o.z = dsilu((a2 - mu)*s + be);
  o.w = dsilu((a3 - mu)*s + be);
  *(float4*)(out + ((long)b*256 + co)*HW + tid*4) = o;
}

// ---------- flash-style attention ----------
// grid = (16 i-tiles, 4 heads, 8 batch), block = 256.
// LDS: q_s[d][i] 16KB, k_s[d][j] 16KB, v_s[j][d^swz] 16KB, s_s 16KB = 64KB exactly.
__global__ __launch_bounds__(256)
void attn_k(const float* __restrict__ qkv, float* __restrict__ out)
{
  const int it = blockIdx.x, h = blockIdx.y, b = blockIdx.z;
  const int tid = threadIdx.x;
  const int i0 = it << 6;
  const int ii = tid >> 2, jg = tid & 3;
  const int jj0 = jg << 4, d0 = jg << 4;
  __shared__ __align__(16) float smem[16384];
  float* q_s = smem;
  float* k_s = smem + 4096;
  float* v_s = smem + 8192;
  float* s_s = smem + 12288;
  const float* qb = qkv + ((long)b*768 + h*64)*HW;
  const float* kb = qb + 256*HW;
  const float* vb = qb + 512*HW;
  // stage Q tile: q_s[d*64 + col]
#pragma unroll
  for (int l = 0; l < 4; l++){
    const int fidx = l*256 + tid;
    const int d = fidx >> 4, c4 = (fidx & 15) << 2;
    const float4 v = *(const float4*)(qb + (long)d*HW + i0 + c4);
    q_s[(d<<6) + c4    ] = v.x;
    q_s[(d<<6) + c4 + 1] = v.y;
    q_s[(d<<6) + c4 + 2] = v.z;
    q_s[(d<<6) + c4 + 3] = v.w;
  }
  float m = -1e30f, lsum = 0.f;
  float O[16];
#pragma unroll
  for (int u = 0; u < 16; u++) O[u] = 0.f;
  __syncthreads();

  const int sswz = (ii & 7) << 2;
  for (int jt = 0; jt < 16; jt++){
    const int j0 = jt << 6;
    // stage K row-major; V transposed with XOR swizzle on d
#pragma unroll
    for (int l = 0; l < 4; l++){
      const int fidx = l*256 + tid;
      const int d = fidx >> 4, c4 = (fidx & 15) << 2;
      const float4 kv = *(const float4*)(kb + (long)d*HW + j0 + c4);
      k_s[(d<<6) + c4    ] = kv.x;
      k_s[(d<<6) + c4 + 1] = kv.y;
      k_s[(d<<6) + c4 + 2] = kv.z;
      k_s[(d<<6) + c4 + 3] = kv.w;
      const float4 vv = *(const float4*)(vb + (long)d*HW + j0 + c4);
      v_s[((c4    )<<6) + (d ^ (((c4    ) & 7) << 2))] = vv.x;
      v_s[((c4 + 1)<<6) + (d ^ (((c4 + 1) & 7) << 2))] = vv.y;
      v_s[((c4 + 2)<<6) + (d ^ (((c4 + 2) & 7) << 2))] = vv.z;
      v_s[((c4 + 3)<<6) + (d ^ (((c4 + 3) & 7) << 2))] = vv.w;
    }
    __syncthreads();
    // S[ii][jj0..jj0+15] = sum_d q[d][ii] * k[d][j]
    float sa[16];
#pragma unroll
    for (int u = 0; u < 16; u++) sa[u] = 0.f;
#pragma unroll 4
    for (int d = 0; d < 64; d++){
      const float qv = q_s[(d<<6) + ii];
      const float4* kp = (const float4*)&k_s[(d<<6) + jj0];
      const float4 k0 = kp[0], k1 = kp[1], k2 = kp[2], k3 = kp[3];
      sa[0] += qv*k0.x; sa[1] += qv*k0.y; sa[2] += qv*k0.z; sa[3] += qv*k0.w;
      sa[4] += qv*k1.x; sa[5] += qv*k1.y; sa[6] += qv*k1.z; sa[7] += qv*k1.w;
      sa[8] += qv*k2.x; sa[9] += qv*k2.y; sa[10]+= qv*k2.z; sa[11]+= qv*k2.w;
      sa[12]+= qv*k3.x; sa[13]+= qv*k3.y; sa[14]+= qv*k3.z; sa[15]+= qv*k3.w;
    }
    // online softmax (quad lanes share row ii)
    float cmax = sa[0];
#pragma unroll
    for (int u = 1; u < 16; u++) cmax = fmaxf(cmax, sa[u]);
    cmax = fmaxf(cmax, __shfl_xor(cmax, 1));
    cmax = fmaxf(cmax, __shfl_xor(cmax, 2));
    const float mnew = fmaxf(m, cmax);
    const float alpha = __expf(m - mnew);
    float ps = 0.f;
    float pv[16];
#pragma unroll
    for (int u = 0; u < 16; u++){ pv[u] = __expf(sa[u] - mnew); ps += pv[u]; }
    ps += __shfl_xor(ps, 1);
    ps += __shfl_xor(ps, 2);
    lsum = lsum*alpha + ps;
    m = mnew;
#pragma unroll
    for (int u = 0; u < 16; u++) O[u] *= alpha;
    // write p (swizzled row ii) — intra-wave producer/consumer, no barrier needed
#pragma unroll
    for (int u = 0; u < 16; u++) s_s[(ii<<6) + ((jj0 + u) ^ sswz)] = pv[u];
    // O[ii][d0..d0+15] += p[ii][j] * v[d][j]
#pragma unroll 4
    for (int j = 0; j < 64; j++){
      const float p = s_s[(ii<<6) + (j ^ sswz)];
      const int jswz = (j & 7) << 2;
      const float4 v0 = *(const float4*)&v_s[(j<<6) + ((d0     ) ^ jswz)];
      const float4 v1 = *(const float4*)&v_s[(j<<6) + ((d0 +  4) ^ jswz)];
      const float4 v2 = *(const float4*)&v_s[(j<<6) + ((d0 +  8) ^ jswz)];
      const float4 v3 = *(const float4*)&v_s[(j<<6) + ((d0 + 12) ^ jswz)];
      O[0] += p*v0.x; O[1] += p*v0.y; O[2] += p*v0.z; O[3] += p*v0.w;
      O[4] += p*v1.x; O[5] += p*v1.y; O[6] += p*v1.z; O[7] += p*v1.w;
      O[8] += p*v2.x; O[9] += p*v2.y; O[10]+= p*v2.z; O[11]+= p*v2.w;
      O[12]+= p*v3.x; O[13]+= p*v3.y; O[14]+= p*v3.z; O[15]+= p*v3.w;
    }
    __syncthreads();
  }
  // normalize, transpose through LDS, coalesced store
  const float rinv = 1.f / lsum;
#pragma unroll
  for (int u = 0; u < 16; u++){
    const int d = d0 + u;
    s_s[(d<<6) + (ii ^ ((u & 7) << 2))] = O[u]*rinv;
  }
  __syncthreads();
  float* ob = out + ((long)b*256 + h*64)*HW;
#pragma unroll
  for (int l = 0; l < 4; l++){
    const int fidx = l*256 + tid;
    const int d = fidx >> 4, c4 = (fidx & 15) << 2;
    const int dswz = (d & 7) << 2;
    float4 o;
    o.x = s_s[(d<<6) + ((c4    ) ^ dswz)];
    o.y = s_s[(d<<6) + ((c4 + 1) ^ dswz)];
    o.z = s_s[(d<<6) + ((c4 + 2) ^ dswz)];
    o.w = s_s[(d<<6) + ((c4 + 3) ^ dswz)];
    *(float4*)(ob + (long)d*HW + i0 + c4) = o;
  }
}

// ---------- final concat(1024ch) 1x1 conv + BN + SiLU -> fp32 out ----------
__global__ __launch_bounds__(256)
void conv_concat_k(const float* __restrict__ s0, const float* __restrict__ s1,
                   const float* __restrict__ s2, const float* __restrict__ s3,
                   const float* __restrict__ w, const float* __restrict__ bnp,
                   float* __restrict__ out)
{
  const int co = blockIdx.x, b = blockIdx.y;   // Cout=512
  const int tid = threadIdx.x;
  __shared__ float wrow[1024];
  for (int i = tid; i < 1024; i += 256) wrow[i] = w[(long)co*1024 + i];
  __syncthreads();
  const int p0 = tid * 4;
  float a0 = 0.f, a1 = 0.f, a2 = 0.f, a3 = 0.f;
  const float* srcs[4];
  srcs[0] = s0 + (long)b*524288 + p0;
  srcs[1] = s1 + (long)b*524288 + p0;
  srcs[2] = s2 + (long)b*262144 + p0;
  srcs[3] = s3 + (long)b*262144 + p0;
#pragma unroll
  for (int seg = 0; seg < 4; seg++){
    const float* sp = srcs[seg];
    const float* wp = wrow + (seg << 8);
#pragma unroll 4
    for (int ci = 0; ci < 256; ci++){
      const float wv = wp[ci];
      const float4 xv = *(const float4*)(sp + (long)ci*HW);
      a0 += wv*xv.x; a1 += wv*xv.y; a2 += wv*xv.z; a3 += wv*xv.w;
    }
  }
  const float g  = bnp[co];
  const float be = bnp[512  + co];
  const float mu = bnp[1024 + co];
  const float va = bnp[1536 + co];
  const float s = g / sqrtf(va + 1e-3f);
  float4 o;
  o.x = dsilu((a0 - mu)*s + be);
  o.y = dsilu((a1 - mu)*s + be);
  o.z = dsilu((a2 - mu)*s + be);
  o.w = dsilu((a3 - mu)*s + be);
  *(float4*)(out + ((long)b*512 + co)*HW + p0) = o;
}

// ---------- host ----------
extern "C" void kernel_launch(void* const* d_in, const int* in_sizes, int n_in,
                              void* d_out, int out_size, void* d_ws, size_t ws_size,
                              hipStream_t stream)
{
  const float* x       = (const float*)d_in[0];
  const float* cv1_w   = (const float*)d_in[1];
  const float* cv1_bn  = (const float*)d_in[2];
  const float* cv2_w   = (const float*)d_in[3];
  const float* cv2_bn  = (const float*)d_in[4];
  const float* mcv1_w  = (const float*)d_in[5];
  const float* mcv1_bn = (const float*)d_in[6];
  const float* mqkv_w  = (const float*)d_in[7];
  const float* mrw     = (const float*)d_in[8];
  const float* mrh     = (const float*)d_in[9];
  const float* mcv2_w  = (const float*)d_in[10];
  const float* mcv2_bn = (const float*)d_in[11];

  float* ws   = (float*)d_ws;
  float* t    = ws;                    // 8*512*1024         = 4,194,304 f
  float* ypad = t    + 4194304;        // 8*256*1224         = 2,506,752 f
  float* z1   = ypad + 2506752;        // 8*256*1024         = 2,097,152 f
  float* qkvb = z1   + 2097152;        // 8*768*1024         = 6,291,456 f
  float* att  = qkvb + 6291456;        // 2,097,152 f
  float* y2   = att  + 2097152;        // 2,097,152 f
  float* y3   = y2   + 2097152;        // 2,097,152 f  (total ~85.5 MB)

  const dim3 blk(256);

  // cv1: x (8,512,1024) -> t (8,512,1024), BN+SiLU
  conv1x1_k<0><<<dim3(512, 8), blk, 0, stream>>>(
      x, 524288, 512, cv1_w, cv1_bn, nullptr, 0, nullptr, nullptr, t, 524288);

  const float* yi = t + 262144;  // y1 = t[:, 256:]
  long yi_bs = 524288;
  float* youts[2] = { y2, y3 };
  for (int i = 0; i < 2; i++){
    pad_k<<<dim3(2048), blk, 0, stream>>>(yi, yi_bs, ypad);
    conv3x3_k<<<dim3(256, 8), blk, 0, stream>>>(
        ypad, mcv1_w + (long)i*589824, mcv1_bn + i*1024, z1);
    conv1x1_k<1><<<dim3(768, 8), blk, 0, stream>>>(
        z1, 262144, 256, mqkv_w + (long)i*196608, nullptr, nullptr, 0,
        mrw + i*8192, mrh + i*8192, qkvb, 786432);
    attn_k<<<dim3(16, 4, 8), blk, 0, stream>>>(qkvb, att);
    conv1x1_k<2><<<dim3(256, 8), blk, 0, stream>>>(
        att, 262144, 256, mcv2_w + (long)i*65536, mcv2_bn + i*1024,
        yi, yi_bs, nullptr, nullptr, youts[i], 262144);
    yi = youts[i]; yi_bs = 262144;
  }

  // concat [y0,y1,y2,y3] -> 1x1 conv 1024->512 + BN + SiLU -> fp32 out
  conv_concat_k<<<dim3(512, 8), blk, 0, stream>>>(
      t, t + 262144, y2, y3, cv2_w, cv2_bn, (float*)d_out);
}

// Round 4
// 454.817 us; speedup vs baseline: 6.5769x; 6.5769x over previous
//
#include <hip/hip_runtime.h>
#include <hip/hip_bf16.h>

typedef unsigned short ushort_t;
typedef __bf16 bf16x8 __attribute__((ext_vector_type(8)));
typedef float f32x4 __attribute__((ext_vector_type(4)));
typedef unsigned short us8 __attribute__((ext_vector_type(8)));

#define AS1 __attribute__((address_space(1)))
#define AS3 __attribute__((address_space(3)))

__device__ __forceinline__ void gld16(const void* g, void* l){
  __builtin_amdgcn_global_load_lds((AS1 void*)(void*)g, (AS3 void*)l, 16, 0, 0);
}
__device__ __forceinline__ f32x4 mfma16(bf16x8 a, bf16x8 b, f32x4 c){
  return __builtin_amdgcn_mfma_f32_16x16x32_bf16(a, b, c, 0, 0, 0);
}
__device__ __forceinline__ unsigned short f2bfu(float f){
  union { float f; unsigned int i; } c; c.f = f;
  unsigned int x = c.i;
  return (unsigned short)((x + 0x7fffu + ((x >> 16) & 1u)) >> 16);  // RNE
}
__device__ __forceinline__ float bfu2f(unsigned short u){
  union { unsigned int i; float f; } c; c.i = ((unsigned int)u) << 16; return c.f;
}
__device__ __forceinline__ float dsilu(float x){ return x / (1.f + __expf(-x)); }

// ---------- x: fp32 NCHW [b][512][1024] -> bf16 NHWC [b][1024][512] ----------
__global__ __launch_bounds__(256)
void transpose_x_k(const float* __restrict__ x, ushort_t* __restrict__ xc)
{
  __shared__ float tl[64*68];
  const int ci0 = blockIdx.x*64, px0 = blockIdx.y*64, b = blockIdx.z;
  const int t = threadIdx.x;
  {
    const int ci_l = t>>2, pc = (t&3)*16;
    const float* src = x + (size_t)b*524288 + (size_t)(ci0+ci_l)*1024 + px0 + pc;
    float* d = &tl[ci_l*68 + pc];
    *(float4*)(d)    = *(const float4*)(src);
    *(float4*)(d+4)  = *(const float4*)(src+4);
    *(float4*)(d+8)  = *(const float4*)(src+8);
    *(float4*)(d+12) = *(const float4*)(src+12);
  }
  __syncthreads();
  {
    const int px_l = t>>2, cc = (t&3)*16;
    us8 o0, o1;
#pragma unroll
    for (int i = 0; i < 8; i++) o0[i] = f2bfu(tl[(cc+i)*68 + px_l]);
#pragma unroll
    for (int i = 0; i < 8; i++) o1[i] = f2bfu(tl[(cc+8+i)*68 + px_l]);
    ushort_t* dst = xc + (size_t)b*524288 + (size_t)(px0+px_l)*512 + ci0 + cc;
    *(us8*)dst = o0; *(us8*)(dst+8) = o1;
  }
}

// ---------- 4-segment flat fp32 -> bf16 ----------
__global__ __launch_bounds__(256)
void cvt4_k(const float* s0, const float* s1, const float* s2, const float* s3,
            ushort_t* d0, ushort_t* d1, ushort_t* d2, ushort_t* d3,
            int n0, int n1, int n2, int n3)
{
  const int seg = blockIdx.y;
  const float* s = (seg==0?s0:seg==1?s1:seg==2?s2:s3);
  ushort_t* d    = (seg==0?d0:seg==1?d1:seg==2?d2:d3);
  const int n4   = (seg==0?n0:seg==1?n1:seg==2?n2:n3) >> 2;
  for (int i = blockIdx.x*256 + threadIdx.x; i < n4; i += gridDim.x*256){
    const float4 v = *(const float4*)(s + (size_t)i*4);
    ushort4 p; p.x=f2bfu(v.x); p.y=f2bfu(v.y); p.z=f2bfu(v.z); p.w=f2bfu(v.w);
    *(ushort4*)(d + (size_t)i*4) = p;
  }
}

// ---------- mcv1_w [n][co][ci][3][3] fp32 -> [n*256+co][tap*256+ci] bf16 ----------
__global__ __launch_bounds__(256)
void reorder3_k(const float* __restrict__ w, ushort_t* __restrict__ o)
{
  const int blk = blockIdx.x;                 // n*256+co
  const float* src = w + (size_t)blk*2304;
  ushort_t* dst = o + (size_t)blk*2304;
  for (int idx = threadIdx.x; idx < 2304; idx += 256){
    const int ci = idx/9, tap = idx - ci*9;
    dst[tap*256 + ci] = f2bfu(src[idx]);
  }
}

// ---------- zero-pad channels-last: [32][32][256] -> [34][34][256] ----------
__global__ __launch_bounds__(256)
void pad_cl_k(const ushort_t* __restrict__ yi, long yi_bs, int yi_rs,
              ushort_t* __restrict__ yp)
{
  const int r = blockIdx.x, b = blockIdx.y;   // r in 0..33
  const ushort_t* src = yi + (size_t)b*yi_bs;
  ushort_t* dst = yp + (size_t)b*295936 + (size_t)r*34*256;
  const int t = threadIdx.x;
  for (int c = 0; c < 34; c++){
    ushort_t v = 0;
    if (r >= 1 && r <= 32 && c >= 1 && c <= 32) v = src[(size_t)((r-1)*32 + (c-1))*yi_rs + t];
    dst[c*256 + t] = v;
  }
}

// ---------- MFMA GEMM: D[m=co][n=px] = A[co][k] * B[k][px] per batch ----------
// BMODE 0: plain channels-last B (row stride Rb, batch stride Bbs)
// BMODE 1: concat-4 (t_cl+0 / t_cl+256 / y2 / y3, strides hardcoded)
// BMODE 2: implicit im2col over padded 34x34x256 buffer
// EPI 0: BN+SiLU -> bf16 cl | 1: qkv (q*=0.125, k+=rw+rh) -> bf16 cl
// EPI 2: BN+SiLU+res -> bf16 cl | 3: BN+SiLU -> fp32 NCHW
template<int BMODE, int EPI>
__global__ __launch_bounds__(256)
void gemm_k(const ushort_t* __restrict__ A, const int M, const int K,
            const ushort_t* __restrict__ B0, const ushort_t* __restrict__ B1,
            const ushort_t* __restrict__ B2, const ushort_t* __restrict__ B3,
            const int Rb, const long Bbs,
            const float* __restrict__ bnp,
            const float* __restrict__ rw, const float* __restrict__ rh,
            const ushort_t* __restrict__ res, const long res_bs, const int res_rs,
            void* __restrict__ outp, const long out_bs, const int out_rs)
{
  const int m0 = blockIdx.x*128, n0 = blockIdx.y*128, b = blockIdx.z;
  const int tid = threadIdx.x, lane = tid & 63, w = tid >> 6;
  const int wm = w & 1, wn = w >> 1, q = lane >> 4, l15 = lane & 15;
  __shared__ __align__(16) ushort_t A_s[128*32];
  __shared__ __align__(16) ushort_t B_s[128*32];

  f32x4 acc[4][4];
#pragma unroll
  for (int mi = 0; mi < 4; mi++)
#pragma unroll
    for (int ni = 0; ni < 4; ni++) acc[mi][ni] = (f32x4){0.f,0.f,0.f,0.f};

  const int crow = lane >> 2;   // row within 16-row chunk
  const int kq   = lane & 3;    // 16B quarter within 32-k row

  const int nsteps = K >> 5;
  for (int ks = 0; ks < nsteps; ks++){
    const int k0 = ks << 5;
#pragma unroll
    for (int p = 0; p < 2; p++){
      const int c = w*2 + p;
      const int row = c*16 + crow;
      // A chunk
      const ushort_t* ga = A + (size_t)(m0 + row)*K + k0 + kq*8;
      gld16(ga, A_s + c*512);
      // B chunk
      const ushort_t* gb;
      if (BMODE == 0){
        gb = B0 + (size_t)b*Bbs + (size_t)(n0 + row)*Rb + k0 + kq*8;
      } else if (BMODE == 1){
        const int seg = k0 >> 8;
        const ushort_t* sb = (seg==0?B0:seg==1?B1:seg==2?B2:B3);
        const int sstr = (seg < 2) ? 512 : 256;
        const long sbs = (seg < 2) ? 524288L : 262144L;
        gb = sb + (size_t)b*sbs + (size_t)(n0 + row)*sstr + (k0 & 255) + kq*8;
      } else {
        const int tap = k0 >> 8, ci0 = k0 & 255;
        const int dy = tap/3, dx = tap - dy*3;
        const int px = n0 + row, y = px >> 5, x = px & 31;
        gb = B0 + (size_t)b*295936L + (size_t)((y+dy)*34 + (x+dx))*256 + ci0 + kq*8;
      }
      gld16(gb, B_s + c*512);
    }
    __syncthreads();
    bf16x8 af[4], bfr[4];
#pragma unroll
    for (int mi = 0; mi < 4; mi++)
      af[mi] = __builtin_bit_cast(bf16x8, *(const us8*)&A_s[(wm*64 + mi*16 + l15)*32 + q*8]);
#pragma unroll
    for (int ni = 0; ni < 4; ni++)
      bfr[ni] = __builtin_bit_cast(bf16x8, *(const us8*)&B_s[(wn*64 + ni*16 + l15)*32 + q*8]);
#pragma unroll
    for (int mi = 0; mi < 4; mi++)
#pragma unroll
      for (int ni = 0; ni < 4; ni++)
        acc[mi][ni] = mfma16(af[mi], bfr[ni], acc[mi][ni]);
    __syncthreads();
  }

  // ---- epilogue ----
  const int m_w = m0 + wm*64, n_w = n0 + wn*64;
#pragma unroll
  for (int mi = 0; mi < 4; mi++){
    const int mb = m_w + mi*16 + q*4;      // 4 consecutive co
    float sc[4], off[4];
    if (EPI != 1){
      const float4 g  = *(const float4*)(bnp + mb);
      const float4 be = *(const float4*)(bnp + M + mb);
      const float4 mu = *(const float4*)(bnp + 2*M + mb);
      const float4 va = *(const float4*)(bnp + 3*M + mb);
      sc[0] = g.x/sqrtf(va.x+1e-3f); off[0] = be.x - mu.x*sc[0];
      sc[1] = g.y/sqrtf(va.y+1e-3f); off[1] = be.y - mu.y*sc[1];
      sc[2] = g.z/sqrtf(va.z+1e-3f); off[2] = be.z - mu.z*sc[2];
      sc[3] = g.w/sqrtf(va.w+1e-3f); off[3] = be.w - mu.w*sc[3];
    }
    const int region = mb >> 8;
#pragma unroll
    for (int ni = 0; ni < 4; ni++){
      const int n_g = n_w + ni*16 + l15;
      f32x4 v = acc[mi][ni];
      float o[4];
#pragma unroll
      for (int r = 0; r < 4; r++){
        float xv = v[r];
        if (EPI == 1){
          if (region == 0) xv *= 0.125f;
          else if (region == 1){
            const int c64 = mb + r - 256;
            xv += rw[c64*32 + (n_g & 31)] + rh[c64*32 + (n_g >> 5)];
          }
        } else {
          xv = dsilu(xv*sc[r] + off[r]);
          if (EPI == 2)
            xv += bfu2f(res[(size_t)b*res_bs + (size_t)n_g*res_rs + mb + r]);
        }
        o[r] = xv;
      }
      if (EPI == 3){
        float* of = (float*)outp + (size_t)b*out_bs;
#pragma unroll
        for (int r = 0; r < 4; r++) of[(size_t)(mb + r)*1024 + n_g] = o[r];
      } else {
        ushort4 pk; pk.x=f2bfu(o[0]); pk.y=f2bfu(o[1]); pk.z=f2bfu(o[2]); pk.w=f2bfu(o[3]);
        *(ushort4*)((ushort_t*)outp + (size_t)b*out_bs + (size_t)n_g*out_rs + mb) = pk;
      }
    }
  }
}

// ---------- flash attention, bf16 MFMA ----------
// grid (16 i-tiles, 4 heads, 8 batch), 256 thr = 4 waves; wave w owns rows w*16..w*16+15
__global__ __launch_bounds__(256)
void attn_k(const ushort_t* __restrict__ qkv, ushort_t* __restrict__ out)
{
  const int it = blockIdx.x, h = blockIdx.y, b = blockIdx.z;
  const int tid = threadIdx.x, lane = tid & 63, w = tid >> 6;
  const int q = lane >> 4, l15 = lane & 15;
  const int i0 = it*64;
  __shared__ __align__(16) ushort_t K_s[64*72];
  __shared__ __align__(16) ushort_t V_s[64*72];
  __shared__ __align__(16) ushort_t P_s[64*72];
  const ushort_t* qb = qkv + (size_t)b*786432;

  bf16x8 qf[2];
  {
    const ushort_t* qr = qb + (size_t)(i0 + w*16 + l15)*768 + h*64 + q*8;
    qf[0] = __builtin_bit_cast(bf16x8, *(const us8*)qr);
    qf[1] = __builtin_bit_cast(bf16x8, *(const us8*)(qr + 32));
  }
  f32x4 oacc[4];
#pragma unroll
  for (int nd = 0; nd < 4; nd++) oacc[nd] = (f32x4){0.f,0.f,0.f,0.f};
  float m_r[4] = {-3e38f,-3e38f,-3e38f,-3e38f};
  float l_r[4] = {0.f,0.f,0.f,0.f};

  for (int jt = 0; jt < 16; jt++){
    const int j0 = jt*64;
    __syncthreads();
    { // stage K rows [j][d]
      const int j = tid >> 2, dg = tid & 3;
      const ushort_t* src = qb + (size_t)(j0 + j)*768 + 256 + h*64 + dg*16;
      const us8 a = *(const us8*)src; const us8 c = *(const us8*)(src + 8);
      *(us8*)&K_s[j*72 + dg*16] = a;
      *(us8*)&K_s[j*72 + dg*16 + 8] = c;
    }
    { // stage V transposed: V_s[d][j]
      const int j = tid & 63, dg = tid >> 6;
      const ushort_t* src = qb + (size_t)(j0 + j)*768 + 512 + h*64 + dg*16;
      const us8 a = *(const us8*)src; const us8 c = *(const us8*)(src + 8);
#pragma unroll
      for (int dd = 0; dd < 8; dd++) V_s[(dg*16 + dd)*72 + j] = a[dd];
#pragma unroll
      for (int dd = 0; dd < 8; dd++) V_s[(dg*16 + 8 + dd)*72 + j] = c[dd];
    }
    __syncthreads();
    // S = Q K^T  (16 rows x 64 cols per wave)
    f32x4 sacc[4];
#pragma unroll
    for (int ni = 0; ni < 4; ni++) sacc[ni] = (f32x4){0.f,0.f,0.f,0.f};
#pragma unroll
    for (int ks = 0; ks < 2; ks++){
#pragma unroll
      for (int ni = 0; ni < 4; ni++){
        const bf16x8 kf = __builtin_bit_cast(bf16x8, *(const us8*)&K_s[(ni*16 + l15)*72 + ks*32 + q*8]);
        sacc[ni] = mfma16(qf[ks], kf, sacc[ni]);
      }
    }
    // online softmax, rows r (row = q*4+r), cols distributed over 16 lanes x 4 ni
    float p[4][4];   // [ni][r]
    float alpha[4];
#pragma unroll
    for (int r = 0; r < 4; r++){
      float mx = fmaxf(fmaxf(sacc[0][r], sacc[1][r]), fmaxf(sacc[2][r], sacc[3][r]));
      mx = fmaxf(mx, __shfl_xor(mx, 1));
      mx = fmaxf(mx, __shfl_xor(mx, 2));
      mx = fmaxf(mx, __shfl_xor(mx, 4));
      mx = fmaxf(mx, __shfl_xor(mx, 8));
      const float mnew = fmaxf(m_r[r], mx);
      alpha[r] = __expf(m_r[r] - mnew);
      m_r[r] = mnew;
      float ps = 0.f;
#pragma unroll
      for (int ni = 0; ni < 4; ni++){ p[ni][r] = __expf(sacc[ni][r] - mnew); ps += p[ni][r]; }
      ps += __shfl_xor(ps, 1);
      ps += __shfl_xor(ps, 2);
      ps += __shfl_xor(ps, 4);
      ps += __shfl_xor(ps, 8);
      l_r[r] = l_r[r]*alpha[r] + ps;
    }
#pragma unroll
    for (int nd = 0; nd < 4; nd++)
#pragma unroll
      for (int r = 0; r < 4; r++) oacc[nd][r] *= alpha[r];
    // write P (wave-private rows)
#pragma unroll
    for (int ni = 0; ni < 4; ni++)
#pragma unroll
      for (int r = 0; r < 4; r++)
        P_s[(w*16 + q*4 + r)*72 + ni*16 + l15] = f2bfu(p[ni][r]);
    // O += P V
#pragma unroll
    for (int ks = 0; ks < 2; ks++){
      const bf16x8 pa = __builtin_bit_cast(bf16x8, *(const us8*)&P_s[(w*16 + l15)*72 + ks*32 + q*8]);
#pragma unroll
      for (int nd = 0; nd < 4; nd++){
        const bf16x8 vb = __builtin_bit_cast(bf16x8, *(const us8*)&V_s[(nd*16 + l15)*72 + ks*32 + q*8]);
        oacc[nd] = mfma16(pa, vb, oacc[nd]);
      }
    }
  }
  // epilogue: normalize + store channels-last
  ushort_t* ob = out + (size_t)b*262144;
#pragma unroll
  for (int r = 0; r < 4; r++){
    const float rinv = 1.f / l_r[r];
    const size_t rowo = (size_t)(i0 + w*16 + q*4 + r)*256 + h*64 + l15;
#pragma unroll
    for (int nd = 0; nd < 4; nd++)
      ob[rowo + nd*16] = f2bfu(oacc[nd][r]*rinv);
  }
}

// ---------- host ----------
extern "C" void kernel_launch(void* const* d_in, const int* in_sizes, int n_in,
                              void* d_out, int out_size, void* d_ws, size_t ws_size,
                              hipStream_t stream)
{
  const float* x       = (const float*)d_in[0];
  const float* cv1_w   = (const float*)d_in[1];
  const float* cv1_bn  = (const float*)d_in[2];
  const float* cv2_w   = (const float*)d_in[3];
  const float* cv2_bn  = (const float*)d_in[4];
  const float* mcv1_w  = (const float*)d_in[5];
  const float* mcv1_bn = (const float*)d_in[6];
  const float* mqkv_w  = (const float*)d_in[7];
  const float* mrw     = (const float*)d_in[8];
  const float* mrh     = (const float*)d_in[9];
  const float* mcv2_w  = (const float*)d_in[10];
  const float* mcv2_bn = (const float*)d_in[11];

  ushort_t* uw = (ushort_t*)d_ws;
  ushort_t* x_cl    = uw;                  // 4,194,304
  ushort_t* t_cl    = x_cl    + 4194304;   // 4,194,304
  ushort_t* wb_cv1  = t_cl    + 4194304;   //   262,144
  ushort_t* wb_cv2  = wb_cv1  + 262144;    //   524,288
  ushort_t* wb_qkv  = wb_cv2  + 524288;    //   393,216
  ushort_t* wb_mcv2 = wb_qkv  + 393216;    //   131,072
  ushort_t* wb_mcv1 = wb_mcv2 + 131072;    // 1,179,648
  ushort_t* ypad    = wb_mcv1 + 1179648;   // 2,367,488
  ushort_t* z1_cl   = ypad    + 2367488;   // 2,097,152
  ushort_t* qkv_cl  = z1_cl   + 2097152;   // 6,291,456
  ushort_t* att_cl  = qkv_cl  + 6291456;   // 2,097,152
  ushort_t* y2_cl   = att_cl  + 2097152;   // 2,097,152
  ushort_t* y3_cl   = y2_cl   + 2097152;   // 2,097,152

  const dim3 blk(256);

  transpose_x_k<<<dim3(8,16,8), blk, 0, stream>>>(x, x_cl);
  cvt4_k<<<dim3(256,4), blk, 0, stream>>>(cv1_w, cv2_w, mqkv_w, mcv2_w,
                                          wb_cv1, wb_cv2, wb_qkv, wb_mcv2,
                                          262144, 524288, 393216, 131072);
  reorder3_k<<<dim3(512), blk, 0, stream>>>(mcv1_w, wb_mcv1);

  // cv1: [512 co][512 ci] x x_cl -> t_cl
  gemm_k<0,0><<<dim3(4,8,8), blk, 0, stream>>>(
      wb_cv1, 512, 512, x_cl, nullptr, nullptr, nullptr, 512, 524288L,
      cv1_bn, nullptr, nullptr, nullptr, 0, 0, t_cl, 524288L, 512);

  const ushort_t* yi = t_cl + 256;  long yi_bs = 524288; int yi_rs = 512;
  ushort_t* youts[2] = { y2_cl, y3_cl };
  for (int i = 0; i < 2; i++){
    pad_cl_k<<<dim3(34,8), blk, 0, stream>>>(yi, yi_bs, yi_rs, ypad);
    gemm_k<2,0><<<dim3(2,8,8), blk, 0, stream>>>(
        wb_mcv1 + (size_t)i*589824, 256, 2304, ypad, nullptr, nullptr, nullptr, 0, 0,
        mcv1_bn + i*1024, nullptr, nullptr, nullptr, 0, 0, z1_cl, 262144L, 256);
    gemm_k<0,1><<<dim3(6,8,8), blk, 0, stream>>>(
        wb_qkv + (size_t)i*196608, 768, 256, z1_cl, nullptr, nullptr, nullptr, 256, 262144L,
        nullptr, mrw + i*8192, mrh + i*8192, nullptr, 0, 0, qkv_cl, 786432L, 768);
    attn_k<<<dim3(16,4,8), blk, 0, stream>>>(qkv_cl, att_cl);
    gemm_k<0,2><<<dim3(2,8,8), blk, 0, stream>>>(
        wb_mcv2 + (size_t)i*65536, 256, 256, att_cl, nullptr, nullptr, nullptr, 256, 262144L,
        mcv2_bn + i*1024, nullptr, nullptr, yi, yi_bs, yi_rs, youts[i], 262144L, 256);
    yi = youts[i]; yi_bs = 262144; yi_rs = 256;
  }

  // concat [y0|y1|y2|y3] 1024ch -> 512, fp32 NCHW out
  gemm_k<1,3><<<dim3(4,8,8), blk, 0, stream>>>(
      wb_cv2, 512, 1024, t_cl, t_cl + 256, y2_cl, y3_cl, 0, 0,
      cv2_bn, nullptr, nullptr, nullptr, 0, 0, (float*)d_out, 524288L, 0);
}

// Round 6
// 386.627 us; speedup vs baseline: 7.7368x; 1.1764x over previous
//
#include <hip/hip_runtime.h>
#include <hip/hip_bf16.h>

typedef unsigned short ushort_t;
typedef __bf16 bf16x8 __attribute__((ext_vector_type(8)));
typedef float f32x4 __attribute__((ext_vector_type(4)));
typedef unsigned short us8 __attribute__((ext_vector_type(8)));

#define AS1 __attribute__((address_space(1)))
#define AS3 __attribute__((address_space(3)))

__device__ __forceinline__ void gld16(const void* g, void* l){
  __builtin_amdgcn_global_load_lds((AS1 void*)(void*)g, (AS3 void*)l, 16, 0, 0);
}
__device__ __forceinline__ f32x4 mfma16(bf16x8 a, bf16x8 b, f32x4 c){
  return __builtin_amdgcn_mfma_f32_16x16x32_bf16(a, b, c, 0, 0, 0);
}
__device__ __forceinline__ unsigned short f2bfu(float f){
  union { float f; unsigned int i; } c; c.f = f;
  unsigned int x = c.i;
  return (unsigned short)((x + 0x7fffu + ((x >> 16) & 1u)) >> 16);  // RNE
}
__device__ __forceinline__ float bfu2f(unsigned short u){
  union { unsigned int i; float f; } c; c.i = ((unsigned int)u) << 16; return c.f;
}
__device__ __forceinline__ float dsilu(float x){ return x / (1.f + __expf(-x)); }

// ---------- x: fp32 NCHW [b][512][1024] -> bf16 NHWC [b][1024][512] ----------
__global__ __launch_bounds__(256)
void transpose_x_k(const float* __restrict__ x, ushort_t* __restrict__ xc)
{
  __shared__ float tl[64*68];
  const int ci0 = blockIdx.x*64, px0 = blockIdx.y*64, b = blockIdx.z;
  const int t = threadIdx.x;
  {
    const int ci_l = t>>2, pc = (t&3)*16;
    const float* src = x + (size_t)b*524288 + (size_t)(ci0+ci_l)*1024 + px0 + pc;
    float* d = &tl[ci_l*68 + pc];
    *(float4*)(d)    = *(const float4*)(src);
    *(float4*)(d+4)  = *(const float4*)(src+4);
    *(float4*)(d+8)  = *(const float4*)(src+8);
    *(float4*)(d+12) = *(const float4*)(src+12);
  }
  __syncthreads();
  {
    const int px_l = t>>2, cc = (t&3)*16;
    us8 o0, o1;
#pragma unroll
    for (int i = 0; i < 8; i++) o0[i] = f2bfu(tl[(cc+i)*68 + px_l]);
#pragma unroll
    for (int i = 0; i < 8; i++) o1[i] = f2bfu(tl[(cc+8+i)*68 + px_l]);
    ushort_t* dst = xc + (size_t)b*524288 + (size_t)(px0+px_l)*512 + ci0 + cc;
    *(us8*)dst = o0; *(us8*)(dst+8) = o1;
  }
}

// ---------- 4-segment flat fp32 -> bf16 ----------
__global__ __launch_bounds__(256)
void cvt4_k(const float* s0, const float* s1, const float* s2, const float* s3,
            ushort_t* d0, ushort_t* d1, ushort_t* d2, ushort_t* d3,
            int n0, int n1, int n2, int n3)
{
  const int seg = blockIdx.y;
  const float* s = (seg==0?s0:seg==1?s1:seg==2?s2:s3);
  ushort_t* d    = (seg==0?d0:seg==1?d1:seg==2?d2:d3);
  const int n4   = (seg==0?n0:seg==1?n1:seg==2?n2:n3) >> 2;
  for (int i = blockIdx.x*256 + threadIdx.x; i < n4; i += gridDim.x*256){
    const float4 v = *(const float4*)(s + (size_t)i*4);
    ushort4 p; p.x=f2bfu(v.x); p.y=f2bfu(v.y); p.z=f2bfu(v.z); p.w=f2bfu(v.w);
    *(ushort4*)(d + (size_t)i*4) = p;
  }
}

// ---------- mcv1_w [n][co][ci][3][3] fp32 -> [n*256+co][tap*256+ci] bf16 ----------
__global__ __launch_bounds__(256)
void reorder3_k(const float* __restrict__ w, ushort_t* __restrict__ o)
{
  const int blk = blockIdx.x;                 // n*256+co
  const float* src = w + (size_t)blk*2304;
  ushort_t* dst = o + (size_t)blk*2304;
  for (int idx = threadIdx.x; idx < 2304; idx += 256){
    const int ci = idx/9, tap = idx - ci*9;
    dst[tap*256 + ci] = f2bfu(src[idx]);
  }
}

// ---------- zero-pad channels-last: [32][32][256] -> [34][34][256] ----------
__global__ __launch_bounds__(256)
void pad_cl_k(const ushort_t* __restrict__ yi, long yi_bs, int yi_rs,
              ushort_t* __restrict__ yp)
{
  const int r = blockIdx.x, b = blockIdx.y;   // r in 0..33
  const ushort_t* src = yi + (size_t)b*yi_bs;
  ushort_t* dst = yp + (size_t)b*295936 + (size_t)r*34*256;
  const int t = threadIdx.x;
  for (int c = 0; c < 34; c++){
    ushort_t v = 0;
    if (r >= 1 && r <= 32 && c >= 1 && c <= 32) v = src[(size_t)((r-1)*32 + (c-1))*yi_rs + t];
    dst[c*256 + t] = v;
  }
}

// ---------- MFMA GEMM: D[m=co][n=px] = A[co][k] * B[k][px] per batch ----------
// Tile 64 x NT, 4 waves (wave w owns n-slice w*NT/4). Split-K via blockIdx.z = part*8+b.
// BMODE 0: plain channels-last B | 1: concat-4 | 2: implicit im2col over padded 34x34x256
// EPI 0: BN+SiLU -> bf16 cl | 1: qkv | 2: BN+SiLU+res -> bf16 cl | 3: BN+SiLU -> fp32 NCHW
// EPI 4: raw fp32 partial, channels-last [part*8+b][px][co]
template<int BMODE, int EPI, int NT>
__global__ __launch_bounds__(256, 4)
void gemm_k(const ushort_t* __restrict__ A, const int M, const int K, const int kplen,
            const ushort_t* __restrict__ B0, const ushort_t* __restrict__ B1,
            const ushort_t* __restrict__ B2, const ushort_t* __restrict__ B3,
            const int Rb, const long Bbs,
            const float* __restrict__ bnp,
            const float* __restrict__ rw, const float* __restrict__ rh,
            const ushort_t* __restrict__ res, const long res_bs, const int res_rs,
            void* __restrict__ outp, const long out_bs, const int out_rs)
{
  constexpr int NW = NT/4;          // n-width per wave
  constexpr int NF = NW/16;         // n-fragments per wave
  constexpr int CH = 4 + NT/16;     // total 16-row chunks (A=4, B=NT/16)
  constexpr int CPW = CH/4;         // chunks per wave
  const int m0 = blockIdx.x*64, n0 = blockIdx.y*NT;
  const int bz = blockIdx.z, b = bz & 7, part = bz >> 3;
  const int tid = threadIdx.x, lane = tid & 63, w = tid >> 6;
  const int q = lane >> 4, l15 = lane & 15;
  const int crow = lane >> 2, kq = lane & 3;
  const int gq = kq ^ ((crow>>1)&3);            // swizzled global quarter (loader)
  const int slot = q ^ ((l15>>1)&3);            // swizzled LDS slot (reader)
  __shared__ __align__(16) ushort_t A_s[64*32];
  __shared__ __align__(16) ushort_t B_s[NT*32];

  f32x4 acc[4][NF];
#pragma unroll
  for (int mi = 0; mi < 4; mi++)
#pragma unroll
    for (int ni = 0; ni < NF; ni++) acc[mi][ni] = (f32x4){0.f,0.f,0.f,0.f};

  const int kbeg = part*kplen, kend_ = kbeg + kplen;
  for (int k0 = kbeg; k0 < kend_; k0 += 32){
    const int kk = k0 + gq*8;
#pragma unroll
    for (int p = 0; p < CPW; p++){
      const int c = w*CPW + p;
      if (c < 4){
        const int row = c*16 + crow;
        gld16(A + (size_t)(m0 + row)*K + kk, A_s + c*512);
      } else {
        const int row = (c-4)*16 + crow;
        const ushort_t* gb;
        if (BMODE == 0){
          gb = B0 + (size_t)b*Bbs + (size_t)(n0 + row)*Rb + kk;
        } else if (BMODE == 1){
          const int seg = kk >> 8;
          const ushort_t* sb = (seg==0?B0:seg==1?B1:seg==2?B2:B3);
          const int sstr = (seg < 2) ? 512 : 256;
          const long sbs = (seg < 2) ? 524288L : 262144L;
          gb = sb + (size_t)b*sbs + (size_t)(n0 + row)*sstr + (kk & 255);
        } else {
          const int tap = kk >> 8, ci = kk & 255;
          const int dy = tap/3, dx = tap - dy*3;
          const int px = n0 + row, y = px >> 5, x = px & 31;
          gb = B0 + (size_t)b*295936L + (size_t)((y+dy)*34 + (x+dx))*256 + ci;
        }
        gld16(gb, B_s + (c-4)*512);
      }
    }
    __syncthreads();
    bf16x8 af[4], bfr[NF];
#pragma unroll
    for (int mi = 0; mi < 4; mi++)
      af[mi] = __builtin_bit_cast(bf16x8, *(const us8*)&A_s[(mi*16 + l15)*32 + slot*8]);
#pragma unroll
    for (int ni = 0; ni < NF; ni++)
      bfr[ni] = __builtin_bit_cast(bf16x8, *(const us8*)&B_s[(w*NW + ni*16 + l15)*32 + slot*8]);
#pragma unroll
    for (int mi = 0; mi < 4; mi++)
#pragma unroll
      for (int ni = 0; ni < NF; ni++)
        acc[mi][ni] = mfma16(af[mi], bfr[ni], acc[mi][ni]);
    __syncthreads();
  }

  // ---- epilogue ----
  const int n_w = n0 + w*NW;
#pragma unroll
  for (int mi = 0; mi < 4; mi++){
    const int mb = m0 + mi*16 + q*4;      // 4 consecutive co
    float sc[4], off[4];
    if (EPI != 1 && EPI != 4){
      const float4 g  = *(const float4*)(bnp + mb);
      const float4 be = *(const float4*)(bnp + M + mb);
      const float4 mu = *(const float4*)(bnp + 2*M + mb);
      const float4 va = *(const float4*)(bnp + 3*M + mb);
      sc[0] = g.x/sqrtf(va.x+1e-3f); off[0] = be.x - mu.x*sc[0];
      sc[1] = g.y/sqrtf(va.y+1e-3f); off[1] = be.y - mu.y*sc[1];
      sc[2] = g.z/sqrtf(va.z+1e-3f); off[2] = be.z - mu.z*sc[2];
      sc[3] = g.w/sqrtf(va.w+1e-3f); off[3] = be.w - mu.w*sc[3];
    }
    const int region = mb >> 8;
#pragma unroll
    for (int ni = 0; ni < NF; ni++){
      const int n_g = n_w + ni*16 + l15;
      f32x4 v = acc[mi][ni];
      if (EPI == 4){
        *(float4*)((float*)outp + ((size_t)(part*8 + b)*1024 + n_g)*256 + mb) =
            (float4){v[0], v[1], v[2], v[3]};
        continue;
      }
      float o[4];
#pragma unroll
      for (int r = 0; r < 4; r++){
        float xv = v[r];
        if (EPI == 1){
          if (region == 0) xv *= 0.125f;
          else if (region == 1){
            const int c64 = mb + r - 256;
            xv += rw[c64*32 + (n_g & 31)] + rh[c64*32 + (n_g >> 5)];
          }
        } else {
          xv = dsilu(xv*sc[r] + off[r]);
          if (EPI == 2)
            xv += bfu2f(res[(size_t)b*res_bs + (size_t)n_g*res_rs + mb + r]);
        }
        o[r] = xv;
      }
      if (EPI == 3){
        float* of = (float*)outp + (size_t)b*out_bs;
#pragma unroll
        for (int r = 0; r < 4; r++) of[(size_t)(mb + r)*1024 + n_g] = o[r];
      } else {
        ushort4 pk; pk.x=f2bfu(o[0]); pk.y=f2bfu(o[1]); pk.z=f2bfu(o[2]); pk.w=f2bfu(o[3]);
        *(ushort4*)((ushort_t*)outp + (size_t)b*out_bs + (size_t)n_g*out_rs + mb) = pk;
      }
    }
  }
}

// ---------- split-K reduce (2 parts) + BN + SiLU -> bf16 channels-last ----------
__global__ __launch_bounds__(256)
void reduce3_k(const float* __restrict__ pbuf, const float* __restrict__ bnp,
               ushort_t* __restrict__ out)
{
  const int idx = blockIdx.x*256 + threadIdx.x;   // (b,px,co4), co4 fastest
  const int co = (idx & 63)*4;
  const size_t e = (size_t)idx*4;
  float4 a = *(const float4*)(pbuf + e);
  const float4 c = *(const float4*)(pbuf + 2097152 + e);
  a.x += c.x; a.y += c.y; a.z += c.z; a.w += c.w;
  const float4 g  = *(const float4*)(bnp + co);
  const float4 be = *(const float4*)(bnp + 256 + co);
  const float4 mu = *(const float4*)(bnp + 512 + co);
  const float4 va = *(const float4*)(bnp + 768 + co);
  float s0 = g.x/sqrtf(va.x+1e-3f), s1 = g.y/sqrtf(va.y+1e-3f);
  float s2 = g.z/sqrtf(va.z+1e-3f), s3 = g.w/sqrtf(va.w+1e-3f);
  ushort4 pk;
  pk.x = f2bfu(dsilu((a.x - mu.x)*s0 + be.x));
  pk.y = f2bfu(dsilu((a.y - mu.y)*s1 + be.y));
  pk.z = f2bfu(dsilu((a.z - mu.z)*s2 + be.z));
  pk.w = f2bfu(dsilu((a.w - mu.w)*s3 + be.w));
  *(ushort4*)(out + e) = pk;
}

// ---------- flash attention, bf16 MFMA ----------
__global__ __launch_bounds__(256)
void attn_k(const ushort_t* __restrict__ qkv, ushort_t* __restrict__ out)
{
  const int it = blockIdx.x, h = blockIdx.y, b = blockIdx.z;
  const int tid = threadIdx.x, lane = tid & 63, w = tid >> 6;
  const int q = lane >> 4, l15 = lane & 15;
  const int i0 = it*64;
  __shared__ __align__(16) ushort_t K_s[64*72];
  __shared__ __align__(16) ushort_t V_s[64*72];
  __shared__ __align__(16) ushort_t P_s[64*72];
  const ushort_t* qb = qkv + (size_t)b*786432;

  bf16x8 qf[2];
  {
    const ushort_t* qr = qb + (size_t)(i0 + w*16 + l15)*768 + h*64 + q*8;
    qf[0] = __builtin_bit_cast(bf16x8, *(const us8*)qr);
    qf[1] = __builtin_bit_cast(bf16x8, *(const us8*)(qr + 32));
  }
  f32x4 oacc[4];
#pragma unroll
  for (int nd = 0; nd < 4; nd++) oacc[nd] = (f32x4){0.f,0.f,0.f,0.f};
  float m_r[4] = {-3e38f,-3e38f,-3e38f,-3e38f};
  float l_r[4] = {0.f,0.f,0.f,0.f};

  for (int jt = 0; jt < 16; jt++){
    const int j0 = jt*64;
    __syncthreads();
    { // stage K rows [j][d]
      const int j = tid >> 2, dg = tid & 3;
      const ushort_t* src = qb + (size_t)(j0 + j)*768 + 256 + h*64 + dg*16;
      const us8 a = *(const us8*)src; const us8 c = *(const us8*)(src + 8);
      *(us8*)&K_s[j*72 + dg*16] = a;
      *(us8*)&K_s[j*72 + dg*16 + 8] = c;
    }
    { // stage V transposed: V_s[d][j]
      const int j = tid & 63, dg = tid >> 6;
      const ushort_t* src = qb + (size_t)(j0 + j)*768 + 512 + h*64 + dg*16;
      const us8 a = *(const us8*)src; const us8 c = *(const us8*)(src + 8);
#pragma unroll
      for (int dd = 0; dd < 8; dd++) V_s[(dg*16 + dd)*72 + j] = a[dd];
#pragma unroll
      for (int dd = 0; dd < 8; dd++) V_s[(dg*16 + 8 + dd)*72 + j] = c[dd];
    }
    __syncthreads();
    // S = Q K^T
    f32x4 sacc[4];
#pragma unroll
    for (int ni = 0; ni < 4; ni++) sacc[ni] = (f32x4){0.f,0.f,0.f,0.f};
#pragma unroll
    for (int ks = 0; ks < 2; ks++){
#pragma unroll
      for (int ni = 0; ni < 4; ni++){
        const bf16x8 kf = __builtin_bit_cast(bf16x8, *(const us8*)&K_s[(ni*16 + l15)*72 + ks*32 + q*8]);
        sacc[ni] = mfma16(qf[ks], kf, sacc[ni]);
      }
    }
    // online softmax
    float p[4][4];
    float alpha[4];
#pragma unroll
    for (int r = 0; r < 4; r++){
      float mx = fmaxf(fmaxf(sacc[0][r], sacc[1][r]), fmaxf(sacc[2][r], sacc[3][r]));
      mx = fmaxf(mx, __shfl_xor(mx, 1));
      mx = fmaxf(mx, __shfl_xor(mx, 2));
      mx = fmaxf(mx, __shfl_xor(mx, 4));
      mx = fmaxf(mx, __shfl_xor(mx, 8));
      const float mnew = fmaxf(m_r[r], mx);
      alpha[r] = __expf(m_r[r] - mnew);
      m_r[r] = mnew;
      float ps = 0.f;
#pragma unroll
      for (int ni = 0; ni < 4; ni++){ p[ni][r] = __expf(sacc[ni][r] - mnew); ps += p[ni][r]; }
      ps += __shfl_xor(ps, 1);
      ps += __shfl_xor(ps, 2);
      ps += __shfl_xor(ps, 4);
      ps += __shfl_xor(ps, 8);
      l_r[r] = l_r[r]*alpha[r] + ps;
    }
#pragma unroll
    for (int nd = 0; nd < 4; nd++)
#pragma unroll
      for (int r = 0; r < 4; r++) oacc[nd][r] *= alpha[r];
#pragma unroll
    for (int ni = 0; ni < 4; ni++)
#pragma unroll
      for (int r = 0; r < 4; r++)
        P_s[(w*16 + q*4 + r)*72 + ni*16 + l15] = f2bfu(p[ni][r]);
    // O += P V
#pragma unroll
    for (int ks = 0; ks < 2; ks++){
      const bf16x8 pa = __builtin_bit_cast(bf16x8, *(const us8*)&P_s[(w*16 + l15)*72 + ks*32 + q*8]);
#pragma unroll
      for (int nd = 0; nd < 4; nd++){
        const bf16x8 vb = __builtin_bit_cast(bf16x8, *(const us8*)&V_s[(nd*16 + l15)*72 + ks*32 + q*8]);
        oacc[nd] = mfma16(pa, vb, oacc[nd]);
      }
    }
  }
  ushort_t* ob = out + (size_t)b*262144;
#pragma unroll
  for (int r = 0; r < 4; r++){
    const float rinv = 1.f / l_r[r];
    const size_t rowo = (size_t)(i0 + w*16 + q*4 + r)*256 + h*64 + l15;
#pragma unroll
    for (int nd = 0; nd < 4; nd++)
      ob[rowo + nd*16] = f2bfu(oacc[nd][r]*rinv);
  }
}

// ---------- host ----------
extern "C" void kernel_launch(void* const* d_in, const int* in_sizes, int n_in,
                              void* d_out, int out_size, void* d_ws, size_t ws_size,
                              hipStream_t stream)
{
  const float* x       = (const float*)d_in[0];
  const float* cv1_w   = (const float*)d_in[1];
  const float* cv1_bn  = (const float*)d_in[2];
  const float* cv2_w   = (const float*)d_in[3];
  const float* cv2_bn  = (const float*)d_in[4];
  const float* mcv1_w  = (const float*)d_in[5];
  const float* mcv1_bn = (const float*)d_in[6];
  const float* mqkv_w  = (const float*)d_in[7];
  const float* mrw     = (const float*)d_in[8];
  const float* mrh     = (const float*)d_in[9];
  const float* mcv2_w  = (const float*)d_in[10];
  const float* mcv2_bn = (const float*)d_in[11];

  ushort_t* uw = (ushort_t*)d_ws;
  ushort_t* x_cl    = uw;                  // 4,194,304
  ushort_t* t_cl    = x_cl    + 4194304;   // 4,194,304
  ushort_t* wb_cv1  = t_cl    + 4194304;   //   262,144
  ushort_t* wb_cv2  = wb_cv1  + 262144;    //   524,288
  ushort_t* wb_qkv  = wb_cv2  + 524288;    //   393,216
  ushort_t* wb_mcv2 = wb_qkv  + 393216;    //   131,072
  ushort_t* wb_mcv1 = wb_mcv2 + 131072;    // 1,179,648
  ushort_t* ypad    = wb_mcv1 + 1179648;   // 2,367,488
  ushort_t* z1_cl   = ypad    + 2367488;   // 2,097,152
  ushort_t* qkv_cl  = z1_cl   + 2097152;   // 6,291,456
  ushort_t* att_cl  = qkv_cl  + 6291456;   // 2,097,152
  ushort_t* y2_cl   = att_cl  + 2097152;   // 2,097,152
  ushort_t* y3_cl   = y2_cl   + 2097152;   // 2,097,152
  float*    part_f  = (float*)(y3_cl + 2097152);  // 4,194,304 floats (16 MB)

  const dim3 blk(256);

  transpose_x_k<<<dim3(8,16,8), blk, 0, stream>>>(x, x_cl);
  cvt4_k<<<dim3(256,4), blk, 0, stream>>>(cv1_w, cv2_w, mqkv_w, mcv2_w,
                                          wb_cv1, wb_cv2, wb_qkv, wb_mcv2,
                                          262144, 524288, 393216, 131072);
  reorder3_k<<<dim3(512), blk, 0, stream>>>(mcv1_w, wb_mcv1);

  // cv1: [512 co][512 ci] x x_cl -> t_cl (512 blocks)
  gemm_k<0,0,128><<<dim3(8,8,8), blk, 0, stream>>>(
      wb_cv1, 512, 512, 512, x_cl, nullptr, nullptr, nullptr, 512, 524288L,
      cv1_bn, nullptr, nullptr, nullptr, 0, 0, t_cl, 524288L, 512);

  const ushort_t* yi = t_cl + 256;  long yi_bs = 524288; int yi_rs = 512;
  ushort_t* youts[2] = { y2_cl, y3_cl };
  for (int i = 0; i < 2; i++){
    pad_cl_k<<<dim3(34,8), blk, 0, stream>>>(yi, yi_bs, yi_rs, ypad);
    // conv3x3 as implicit-im2col GEMM, split-K x2 (4 m-tiles x 8 n x 16 bz = 512 blocks)
    gemm_k<2,4,128><<<dim3(4,8,16), blk, 0, stream>>>(
        wb_mcv1 + (size_t)i*589824, 256, 2304, 1152, ypad, nullptr, nullptr, nullptr, 0, 0,
        nullptr, nullptr, nullptr, nullptr, 0, 0, part_f, 0, 0);
    reduce3_k<<<dim3(2048), blk, 0, stream>>>(part_f, mcv1_bn + i*1024, z1_cl);
    // qkv (768 blocks)
    gemm_k<0,1,128><<<dim3(12,8,8), blk, 0, stream>>>(
        wb_qkv + (size_t)i*196608, 768, 256, 256, z1_cl, nullptr, nullptr, nullptr, 256, 262144L,
        nullptr, mrw + i*8192, mrh + i*8192, nullptr, 0, 0, qkv_cl, 786432L, 768);
    attn_k<<<dim3(16,4,8), blk, 0, stream>>>(qkv_cl, att_cl);
    // mcv2 + residual (512 blocks, 64x64 tile)
    gemm_k<0,2,64><<<dim3(4,16,8), blk, 0, stream>>>(
        wb_mcv2 + (size_t)i*65536, 256, 256, 256, att_cl, nullptr, nullptr, nullptr, 256, 262144L,
        mcv2_bn + i*1024, nullptr, nullptr, yi, yi_bs, yi_rs, youts[i], 262144L, 256);
    yi = youts[i]; yi_bs = 262144; yi_rs = 256;
  }

  // concat [y0|y1|y2|y3] 1024ch -> 512, fp32 NCHW out (512 blocks)
  gemm_k<1,3,128><<<dim3(8,8,8), blk, 0, stream>>>(
      wb_cv2, 512, 1024, 1024, t_cl, t_cl + 256, y2_cl, y3_cl, 0, 0,
      cv2_bn, nullptr, nullptr, nullptr, 0, 0, (float*)d_out, 524288L, 0);
}

// Round 7
// 369.371 us; speedup vs baseline: 8.0983x; 1.0467x over previous
//
#include <hip/hip_runtime.h>
#include <hip/hip_bf16.h>

typedef unsigned short ushort_t;
typedef __bf16 bf16x8 __attribute__((ext_vector_type(8)));
typedef float f32x4 __attribute__((ext_vector_type(4)));
typedef unsigned short us8 __attribute__((ext_vector_type(8)));

#define AS1 __attribute__((address_space(1)))
#define AS3 __attribute__((address_space(3)))

__device__ __forceinline__ void gld16(const void* g, void* l){
  __builtin_amdgcn_global_load_lds((AS1 void*)(void*)g, (AS3 void*)l, 16, 0, 0);
}
__device__ __forceinline__ f32x4 mfma16(bf16x8 a, bf16x8 b, f32x4 c){
  return __builtin_amdgcn_mfma_f32_16x16x32_bf16(a, b, c, 0, 0, 0);
}
__device__ __forceinline__ unsigned short f2bfu(float f){
  union { float f; unsigned int i; } c; c.f = f;
  unsigned int x = c.i;
  return (unsigned short)((x + 0x7fffu + ((x >> 16) & 1u)) >> 16);  // RNE
}
__device__ __forceinline__ float bfu2f(unsigned short u){
  union { unsigned int i; float f; } c; c.i = ((unsigned int)u) << 16; return c.f;
}
__device__ __forceinline__ float dsilu(float x){ return x / (1.f + __expf(-x)); }

// ---------- x: fp32 NCHW [b][512][1024] -> bf16 NHWC [b][1024][512] ----------
__global__ __launch_bounds__(256)
void transpose_x_k(const float* __restrict__ x, ushort_t* __restrict__ xc)
{
  __shared__ float tl[64*68];
  const int ci0 = blockIdx.x*64, px0 = blockIdx.y*64, b = blockIdx.z;
  const int t = threadIdx.x;
  {
    const int ci_l = t>>2, pc = (t&3)*16;
    const float* src = x + (size_t)b*524288 + (size_t)(ci0+ci_l)*1024 + px0 + pc;
    float* d = &tl[ci_l*68 + pc];
    *(float4*)(d)    = *(const float4*)(src);
    *(float4*)(d+4)  = *(const float4*)(src+4);
    *(float4*)(d+8)  = *(const float4*)(src+8);
    *(float4*)(d+12) = *(const float4*)(src+12);
  }
  __syncthreads();
  {
    const int px_l = t>>2, cc = (t&3)*16;
    us8 o0, o1;
#pragma unroll
    for (int i = 0; i < 8; i++) o0[i] = f2bfu(tl[(cc+i)*68 + px_l]);
#pragma unroll
    for (int i = 0; i < 8; i++) o1[i] = f2bfu(tl[(cc+8+i)*68 + px_l]);
    ushort_t* dst = xc + (size_t)b*524288 + (size_t)(px0+px_l)*512 + ci0 + cc;
    *(us8*)dst = o0; *(us8*)(dst+8) = o1;
  }
}

// ---------- 4-segment flat fp32 -> bf16 ----------
__global__ __launch_bounds__(256)
void cvt4_k(const float* s0, const float* s1, const float* s2, const float* s3,
            ushort_t* d0, ushort_t* d1, ushort_t* d2, ushort_t* d3,
            int n0, int n1, int n2, int n3)
{
  const int seg = blockIdx.y;
  const float* s = (seg==0?s0:seg==1?s1:seg==2?s2:s3);
  ushort_t* d    = (seg==0?d0:seg==1?d1:seg==2?d2:d3);
  const int n4   = (seg==0?n0:seg==1?n1:seg==2?n2:n3) >> 2;
  for (int i = blockIdx.x*256 + threadIdx.x; i < n4; i += gridDim.x*256){
    const float4 v = *(const float4*)(s + (size_t)i*4);
    ushort4 p; p.x=f2bfu(v.x); p.y=f2bfu(v.y); p.z=f2bfu(v.z); p.w=f2bfu(v.w);
    *(ushort4*)(d + (size_t)i*4) = p;
  }
}

// ---------- mcv1_w [n][co][ci][3][3] fp32 -> [n*256+co][tap*256+ci] bf16 ----------
__global__ __launch_bounds__(256)
void reorder3_k(const float* __restrict__ w, ushort_t* __restrict__ o)
{
  const int blk = blockIdx.x;                 // n*256+co
  const float* src = w + (size_t)blk*2304;
  ushort_t* dst = o + (size_t)blk*2304;
  for (int idx = threadIdx.x; idx < 2304; idx += 256){
    const int ci = idx/9, tap = idx - ci*9;
    dst[tap*256 + ci] = f2bfu(src[idx]);
  }
}

// ---------- zero-pad channels-last: [32][32][256] -> [34][34][256] ----------
__global__ __launch_bounds__(256)
void pad_cl_k(const ushort_t* __restrict__ yi, long yi_bs, int yi_rs,
              ushort_t* __restrict__ yp)
{
  const int r = blockIdx.x, b = blockIdx.y;   // r in 0..33
  const ushort_t* src = yi + (size_t)b*yi_bs;
  ushort_t* dst = yp + (size_t)b*295936 + (size_t)r*34*256;
  const int t = threadIdx.x;
  for (int c = 0; c < 34; c++){
    ushort_t v = 0;
    if (r >= 1 && r <= 32 && c >= 1 && c <= 32) v = src[(size_t)((r-1)*32 + (c-1))*yi_rs + t];
    dst[c*256 + t] = v;
  }
}

// ---------- MFMA GEMM: D[m=co][n=px] = A[co][k] * B[k][px] per batch ----------
// Tile 64 x NT, 4 waves. Split-K via blockIdx.z = part*8+b.
// BMODE 0: plain channels-last B | 1: concat-4 | 2: implicit im2col over padded 34x34x256
// EPI 0: BN+SiLU -> bf16 cl | 1: qkv (q/k -> qk buf [px][512]; v -> vtout NCHW [256][1024])
// EPI 2: BN+SiLU+res -> bf16 cl | 3: BN+SiLU -> fp32 NCHW | 4: raw fp32 partial
template<int BMODE, int EPI, int NT>
__global__ __launch_bounds__(256, 4)
void gemm_k(const ushort_t* __restrict__ A, const int M, const int K, const int kplen,
            const ushort_t* __restrict__ B0, const ushort_t* __restrict__ B1,
            const ushort_t* __restrict__ B2, const ushort_t* __restrict__ B3,
            const int Rb, const long Bbs,
            const float* __restrict__ bnp,
            const float* __restrict__ rw, const float* __restrict__ rh,
            const ushort_t* __restrict__ res, const long res_bs, const int res_rs,
            ushort_t* __restrict__ vtout,
            void* __restrict__ outp, const long out_bs, const int out_rs)
{
  constexpr int NW = NT/4;          // n-width per wave
  constexpr int NF = NW/16;         // n-fragments per wave
  constexpr int CH = 4 + NT/16;     // total 16-row chunks (A=4, B=NT/16)
  constexpr int CPW = CH/4;         // chunks per wave
  const int m0 = blockIdx.x*64, n0 = blockIdx.y*NT;
  const int bz = blockIdx.z, b = bz & 7, part = bz >> 3;
  const int tid = threadIdx.x, lane = tid & 63, w = tid >> 6;
  const int q = lane >> 4, l15 = lane & 15;
  const int crow = lane >> 2, kq = lane & 3;
  const int gq = kq ^ ((crow>>1)&3);            // swizzled global quarter (loader)
  const int slot = q ^ ((l15>>1)&3);            // swizzled LDS slot (reader)
  __shared__ __align__(16) ushort_t A_s[64*32];
  __shared__ __align__(16) ushort_t B_s[NT*32];

  f32x4 acc[4][NF];
#pragma unroll
  for (int mi = 0; mi < 4; mi++)
#pragma unroll
    for (int ni = 0; ni < NF; ni++) acc[mi][ni] = (f32x4){0.f,0.f,0.f,0.f};

  const int kbeg = part*kplen, kend_ = kbeg + kplen;
  for (int k0 = kbeg; k0 < kend_; k0 += 32){
    const int kk = k0 + gq*8;
#pragma unroll
    for (int p = 0; p < CPW; p++){
      const int c = w*CPW + p;
      if (c < 4){
        const int row = c*16 + crow;
        gld16(A + (size_t)(m0 + row)*K + kk, A_s + c*512);
      } else {
        const int row = (c-4)*16 + crow;
        const ushort_t* gb;
        if (BMODE == 0){
          gb = B0 + (size_t)b*Bbs + (size_t)(n0 + row)*Rb + kk;
        } else if (BMODE == 1){
          const int seg = kk >> 8;
          const ushort_t* sb = (seg==0?B0:seg==1?B1:seg==2?B2:B3);
          const int sstr = (seg < 2) ? 512 : 256;
          const long sbs = (seg < 2) ? 524288L : 262144L;
          gb = sb + (size_t)b*sbs + (size_t)(n0 + row)*sstr + (kk & 255);
        } else {
          const int tap = kk >> 8, ci = kk & 255;
          const int dy = tap/3, dx = tap - dy*3;
          const int px = n0 + row, y = px >> 5, x = px & 31;
          gb = B0 + (size_t)b*295936L + (size_t)((y+dy)*34 + (x+dx))*256 + ci;
        }
        gld16(gb, B_s + (c-4)*512);
      }
    }
    __syncthreads();
    bf16x8 af[4], bfr[NF];
#pragma unroll
    for (int mi = 0; mi < 4; mi++)
      af[mi] = __builtin_bit_cast(bf16x8, *(const us8*)&A_s[(mi*16 + l15)*32 + slot*8]);
#pragma unroll
    for (int ni = 0; ni < NF; ni++)
      bfr[ni] = __builtin_bit_cast(bf16x8, *(const us8*)&B_s[(w*NW + ni*16 + l15)*32 + slot*8]);
#pragma unroll
    for (int mi = 0; mi < 4; mi++)
#pragma unroll
      for (int ni = 0; ni < NF; ni++)
        acc[mi][ni] = mfma16(af[mi], bfr[ni], acc[mi][ni]);
    __syncthreads();
  }

  // ---- epilogue ----
  const int n_w = n0 + w*NW;
#pragma unroll
  for (int mi = 0; mi < 4; mi++){
    const int mb = m0 + mi*16 + q*4;      // 4 consecutive co
    float sc[4], off[4];
    if (EPI != 1 && EPI != 4){
      const float4 g  = *(const float4*)(bnp + mb);
      const float4 be = *(const float4*)(bnp + M + mb);
      const float4 mu = *(const float4*)(bnp + 2*M + mb);
      const float4 va = *(const float4*)(bnp + 3*M + mb);
      sc[0] = g.x/sqrtf(va.x+1e-3f); off[0] = be.x - mu.x*sc[0];
      sc[1] = g.y/sqrtf(va.y+1e-3f); off[1] = be.y - mu.y*sc[1];
      sc[2] = g.z/sqrtf(va.z+1e-3f); off[2] = be.z - mu.z*sc[2];
      sc[3] = g.w/sqrtf(va.w+1e-3f); off[3] = be.w - mu.w*sc[3];
    }
    const int region = mb >> 8;
#pragma unroll
    for (int ni = 0; ni < NF; ni++){
      const int n_g = n_w + ni*16 + l15;
      f32x4 v = acc[mi][ni];
      if (EPI == 4){
        *(float4*)((float*)outp + ((size_t)(part*8 + b)*1024 + n_g)*256 + mb) =
            (float4){v[0], v[1], v[2], v[3]};
        continue;
      }
      float o[4];
#pragma unroll
      for (int r = 0; r < 4; r++){
        float xv = v[r];
        if (EPI == 1){
          if (region == 0) xv *= 0.125f;
          else if (region == 1){
            const int c64 = mb + r - 256;
            xv += rw[c64*32 + (n_g & 31)] + rh[c64*32 + (n_g >> 5)];
          }
        } else {
          xv = dsilu(xv*sc[r] + off[r]);
          if (EPI == 2)
            xv += bfu2f(res[(size_t)b*res_bs + (size_t)n_g*res_rs + mb + r]);
        }
        o[r] = xv;
      }
      if (EPI == 3){
        float* of = (float*)outp + (size_t)b*out_bs;
#pragma unroll
        for (int r = 0; r < 4; r++) of[(size_t)(mb + r)*1024 + n_g] = o[r];
      } else if (EPI == 1 && region == 2){
        // V -> transposed NCHW vt buffer [b][ch][px]
#pragma unroll
        for (int r = 0; r < 4; r++)
          vtout[(size_t)b*262144 + (size_t)(mb + r - 512)*1024 + n_g] = f2bfu(o[r]);
      } else {
        ushort4 pk; pk.x=f2bfu(o[0]); pk.y=f2bfu(o[1]); pk.z=f2bfu(o[2]); pk.w=f2bfu(o[3]);
        *(ushort4*)((ushort_t*)outp + (size_t)b*out_bs + (size_t)n_g*out_rs + mb) = pk;
      }
    }
  }
}

// ---------- split-K reduce (2 parts) + BN + SiLU -> bf16 channels-last ----------
__global__ __launch_bounds__(256)
void reduce3_k(const float* __restrict__ pbuf, const float* __restrict__ bnp,
               ushort_t* __restrict__ out)
{
  const int idx = blockIdx.x*256 + threadIdx.x;   // (b,px,co4), co4 fastest
  const int co = (idx & 63)*4;
  const size_t e = (size_t)idx*4;
  float4 a = *(const float4*)(pbuf + e);
  const float4 c = *(const float4*)(pbuf + 2097152 + e);
  a.x += c.x; a.y += c.y; a.z += c.z; a.w += c.w;
  const float4 g  = *(const float4*)(bnp + co);
  const float4 be = *(const float4*)(bnp + 256 + co);
  const float4 mu = *(const float4*)(bnp + 512 + co);
  const float4 va = *(const float4*)(bnp + 768 + co);
  float s0 = g.x/sqrtf(va.x+1e-3f), s1 = g.y/sqrtf(va.y+1e-3f);
  float s2 = g.z/sqrtf(va.z+1e-3f), s3 = g.w/sqrtf(va.w+1e-3f);
  ushort4 pk;
  pk.x = f2bfu(dsilu((a.x - mu.x)*s0 + be.x));
  pk.y = f2bfu(dsilu((a.y - mu.y)*s1 + be.y));
  pk.z = f2bfu(dsilu((a.z - mu.z)*s2 + be.z));
  pk.w = f2bfu(dsilu((a.w - mu.w)*s3 + be.w));
  *(ushort4*)(out + e) = pk;
}

// ---------- flash attention v2: async-staged K/V^T, double-buffered ----------
// qk: [b][px][512] (q ch 0-255 pre-scaled, k ch 256-511 with r added)
// vt: [b][256ch][1024px] NCHW bf16
// K_s/V_s rows of 64 ushort (128B), quarter-swizzled: slot = qq ^ (row&7)
__global__ __launch_bounds__(256)
void attn_k(const ushort_t* __restrict__ qk, const ushort_t* __restrict__ vt,
            ushort_t* __restrict__ out)
{
  const int it = blockIdx.x, h = blockIdx.y, b = blockIdx.z;
  const int tid = threadIdx.x, lane = tid & 63, w = tid >> 6;
  const int q = lane >> 4, l15 = lane & 15;
  const int i0 = it*64;
  __shared__ __align__(16) ushort_t K_s[2][4096];
  __shared__ __align__(16) ushort_t V_s[2][4096];
  __shared__ __align__(16) ushort_t P_s[4096];

  const ushort_t* qkb = qk + (size_t)b*524288;
  const ushort_t* vtb = vt + (size_t)b*262144 + (size_t)h*1024*64;

  // staging lane mapping (per-wave chunk c = w*2+p covers rows c*8..c*8+7)
  const int srow = lane >> 3;                 // row within chunk (== row&7)
  const int sgq  = (lane & 7) ^ srow;         // global quarter for LDS slot lane&7

  bf16x8 qf[2];
  {
    const ushort_t* qr = qkb + (size_t)(i0 + w*16 + l15)*512 + h*64 + q*8;
    qf[0] = __builtin_bit_cast(bf16x8, *(const us8*)qr);
    qf[1] = __builtin_bit_cast(bf16x8, *(const us8*)(qr + 32));
  }
  f32x4 oacc[4];
#pragma unroll
  for (int nd = 0; nd < 4; nd++) oacc[nd] = (f32x4){0.f,0.f,0.f,0.f};
  float m_r[4] = {-3e38f,-3e38f,-3e38f,-3e38f};
  float l_r[4] = {0.f,0.f,0.f,0.f};

  // K slot-swizzle for MFMA reads: slot = qq ^ (l15&7), qq = ks*4+q
  const int rs7 = l15 & 7;

#define STAGE(JT, BUF) {                                                        \
    const int j0s = (JT)*64;                                                    \
    _Pragma("unroll")                                                           \
    for (int p = 0; p < 2; p++){                                                \
      const int c = w*2 + p;                                                    \
      const int row = c*8 + srow;                                               \
      gld16(qkb + (size_t)(j0s + row)*512 + 256 + h*64 + sgq*8, &K_s[BUF][c*512]); \
      gld16(vtb + (size_t)row*1024 + j0s + sgq*8, &V_s[BUF][c*512]);            \
    }                                                                           \
  }

  STAGE(0, 0);
  int cur = 0;
  for (int jt = 0; jt < 16; jt++){
    __syncthreads();              // K_s/V_s[cur] staged; all waves done with prev bufs
    if (jt < 15){ STAGE(jt+1, cur^1); }
    // S = Q K^T (16 rows x 64 cols per wave)
    f32x4 sacc[4];
#pragma unroll
    for (int ni = 0; ni < 4; ni++) sacc[ni] = (f32x4){0.f,0.f,0.f,0.f};
#pragma unroll
    for (int ks = 0; ks < 2; ks++){
      const int slot = (ks*4 + q) ^ rs7;
#pragma unroll
      for (int ni = 0; ni < 4; ni++){
        const bf16x8 kf = __builtin_bit_cast(bf16x8,
            *(const us8*)&K_s[cur][(ni*16 + l15)*64 + slot*8]);
        sacc[ni] = mfma16(qf[ks], kf, sacc[ni]);
      }
    }
    // online softmax (rows q*4+r, cols over 16 lanes x 4 ni)
    float p[4][4];
    float alpha[4];
#pragma unroll
    for (int r = 0; r < 4; r++){
      float mx = fmaxf(fmaxf(sacc[0][r], sacc[1][r]), fmaxf(sacc[2][r], sacc[3][r]));
      mx = fmaxf(mx, __shfl_xor(mx, 1));
      mx = fmaxf(mx, __shfl_xor(mx, 2));
      mx = fmaxf(mx, __shfl_xor(mx, 4));
      mx = fmaxf(mx, __shfl_xor(mx, 8));
      const float mnew = fmaxf(m_r[r], mx);
      alpha[r] = __expf(m_r[r] - mnew);
      m_r[r] = mnew;
      float ps = 0.f;
#pragma unroll
      for (int ni = 0; ni < 4; ni++){ p[ni][r] = __expf(sacc[ni][r] - mnew); ps += p[ni][r]; }
      ps += __shfl_xor(ps, 1);
      ps += __shfl_xor(ps, 2);
      ps += __shfl_xor(ps, 4);
      ps += __shfl_xor(ps, 8);
      l_r[r] = l_r[r]*alpha[r] + ps;
    }
#pragma unroll
    for (int nd = 0; nd < 4; nd++)
#pragma unroll
      for (int r = 0; r < 4; r++) oacc[nd][r] *= alpha[r];
    // write P (wave-private rows, swizzled slots)
#pragma unroll
    for (int ni = 0; ni < 4; ni++){
      const int qq_w = ni*2 + (l15 >> 3);
#pragma unroll
      for (int r = 0; r < 4; r++){
        const int prow = w*16 + q*4 + r;
        P_s[prow*64 + (qq_w ^ (prow & 7))*8 + rs7] = f2bfu(p[ni][r]);
      }
    }
    // O += P V  (intra-wave P dependency; LDS ops in-order per wave)
#pragma unroll
    for (int ks = 0; ks < 2; ks++){
      const int slot = (ks*4 + q) ^ rs7;
      const bf16x8 pa = __builtin_bit_cast(bf16x8,
          *(const us8*)&P_s[(w*16 + l15)*64 + slot*8]);
#pragma unroll
      for (int nd = 0; nd < 4; nd++){
        const bf16x8 vb = __builtin_bit_cast(bf16x8,
            *(const us8*)&V_s[cur][(nd*16 + l15)*64 + slot*8]);
        oacc[nd] = mfma16(pa, vb, oacc[nd]);
      }
    }
    cur ^= 1;
  }
#undef STAGE
  ushort_t* ob = out + (size_t)b*262144;
#pragma unroll
  for (int r = 0; r < 4; r++){
    const float rinv = 1.f / l_r[r];
    const size_t rowo = (size_t)(i0 + w*16 + q*4 + r)*256 + h*64 + l15;
#pragma unroll
    for (int nd = 0; nd < 4; nd++)
      ob[rowo + nd*16] = f2bfu(oacc[nd][r]*rinv);
  }
}

// ---------- host ----------
extern "C" void kernel_launch(void* const* d_in, const int* in_sizes, int n_in,
                              void* d_out, int out_size, void* d_ws, size_t ws_size,
                              hipStream_t stream)
{
  const float* x       = (const float*)d_in[0];
  const float* cv1_w   = (const float*)d_in[1];
  const float* cv1_bn  = (const float*)d_in[2];
  const float* cv2_w   = (const float*)d_in[3];
  const float* cv2_bn  = (const float*)d_in[4];
  const float* mcv1_w  = (const float*)d_in[5];
  const float* mcv1_bn = (const float*)d_in[6];
  const float* mqkv_w  = (const float*)d_in[7];
  const float* mrw     = (const float*)d_in[8];
  const float* mrh     = (const float*)d_in[9];
  const float* mcv2_w  = (const float*)d_in[10];
  const float* mcv2_bn = (const float*)d_in[11];

  ushort_t* uw = (ushort_t*)d_ws;
  ushort_t* x_cl    = uw;                  // 4,194,304
  ushort_t* t_cl    = x_cl    + 4194304;   // 4,194,304
  ushort_t* wb_cv1  = t_cl    + 4194304;   //   262,144
  ushort_t* wb_cv2  = wb_cv1  + 262144;    //   524,288
  ushort_t* wb_qkv  = wb_cv2  + 524288;    //   393,216
  ushort_t* wb_mcv2 = wb_qkv  + 393216;    //   131,072
  ushort_t* wb_mcv1 = wb_mcv2 + 131072;    // 1,179,648
  ushort_t* ypad    = wb_mcv1 + 1179648;   // 2,367,488
  ushort_t* z1_cl   = ypad    + 2367488;   // 2,097,152
  ushort_t* qk_cl   = z1_cl   + 2097152;   // 4,194,304  [b][px][512]
  ushort_t* vt_b    = qk_cl   + 4194304;   // 2,097,152  [b][256][1024]
  ushort_t* att_cl  = vt_b    + 2097152;   // 2,097,152
  ushort_t* y2_cl   = att_cl  + 2097152;   // 2,097,152
  ushort_t* y3_cl   = y2_cl   + 2097152;   // 2,097,152
  float*    part_f  = (float*)(y3_cl + 2097152);  // 4,194,304 floats (16 MB)

  const dim3 blk(256);

  transpose_x_k<<<dim3(8,16,8), blk, 0, stream>>>(x, x_cl);
  cvt4_k<<<dim3(256,4), blk, 0, stream>>>(cv1_w, cv2_w, mqkv_w, mcv2_w,
                                          wb_cv1, wb_cv2, wb_qkv, wb_mcv2,
                                          262144, 524288, 393216, 131072);
  reorder3_k<<<dim3(512), blk, 0, stream>>>(mcv1_w, wb_mcv1);

  // cv1: [512 co][512 ci] x x_cl -> t_cl (512 blocks)
  gemm_k<0,0,128><<<dim3(8,8,8), blk, 0, stream>>>(
      wb_cv1, 512, 512, 512, x_cl, nullptr, nullptr, nullptr, 512, 524288L,
      cv1_bn, nullptr, nullptr, nullptr, 0, 0, nullptr, t_cl, 524288L, 512);

  const ushort_t* yi = t_cl + 256;  long yi_bs = 524288; int yi_rs = 512;
  ushort_t* youts[2] = { y2_cl, y3_cl };
  for (int i = 0; i < 2; i++){
    pad_cl_k<<<dim3(34,8), blk, 0, stream>>>(yi, yi_bs, yi_rs, ypad);
    // conv3x3 as implicit-im2col GEMM, split-K x2 (512 blocks)
    gemm_k<2,4,128><<<dim3(4,8,16), blk, 0, stream>>>(
        wb_mcv1 + (size_t)i*589824, 256, 2304, 1152, ypad, nullptr, nullptr, nullptr, 0, 0,
        nullptr, nullptr, nullptr, nullptr, 0, 0, nullptr, part_f, 0, 0);
    reduce3_k<<<dim3(2048), blk, 0, stream>>>(part_f, mcv1_bn + i*1024, z1_cl);
    // qkv (768 blocks): q/k -> qk_cl [px][512], v -> vt_b NCHW
    gemm_k<0,1,128><<<dim3(12,8,8), blk, 0, stream>>>(
        wb_qkv + (size_t)i*196608, 768, 256, 256, z1_cl, nullptr, nullptr, nullptr, 256, 262144L,
        nullptr, mrw + i*8192, mrh + i*8192, nullptr, 0, 0, vt_b, qk_cl, 524288L, 512);
    attn_k<<<dim3(16,4,8), blk, 0, stream>>>(qk_cl, vt_b, att_cl);
    // mcv2 + residual (512 blocks, 64x64 tile)
    gemm_k<0,2,64><<<dim3(4,16,8), blk, 0, stream>>>(
        wb_mcv2 + (size_t)i*65536, 256, 256, 256, att_cl, nullptr, nullptr, nullptr, 256, 262144L,
        mcv2_bn + i*1024, nullptr, nullptr, yi, yi_bs, yi_rs, nullptr, youts[i], 262144L, 256);
    yi = youts[i]; yi_bs = 262144; yi_rs = 256;
  }

  // concat [y0|y1|y2|y3] 1024ch -> 512, fp32 NCHW out (512 blocks)
  gemm_k<1,3,128><<<dim3(8,8,8), blk, 0, stream>>>(
      wb_cv2, 512, 1024, 1024, t_cl, t_cl + 256, y2_cl, y3_cl, 0, 0,
      cv2_bn, nullptr, nullptr, nullptr, 0, 0, nullptr, (float*)d_out, 524288L, 0);
}

// Round 8
// 304.291 us; speedup vs baseline: 9.8303x; 1.2139x over previous
//
#include <hip/hip_runtime.h>
#include <hip/hip_bf16.h>

typedef unsigned short ushort_t;
typedef __bf16 bf16x8 __attribute__((ext_vector_type(8)));
typedef float f32x4 __attribute__((ext_vector_type(4)));
typedef unsigned short us8 __attribute__((ext_vector_type(8)));
typedef unsigned short us4 __attribute__((ext_vector_type(4)));

#define AS1 __attribute__((address_space(1)))
#define AS3 __attribute__((address_space(3)))

#if __has_builtin(__builtin_amdgcn_exp2f)
#define EXP2F __builtin_amdgcn_exp2f
#else
#define EXP2F exp2f
#endif

__device__ __forceinline__ void gld16(const void* g, void* l){
  __builtin_amdgcn_global_load_lds((AS1 void*)(void*)g, (AS3 void*)l, 16, 0, 0);
}
__device__ __forceinline__ f32x4 mfma16(bf16x8 a, bf16x8 b, f32x4 c){
  return __builtin_amdgcn_mfma_f32_16x16x32_bf16(a, b, c, 0, 0, 0);
}
__device__ __forceinline__ unsigned short f2bfu(float f){
  union { float f; unsigned int i; } c; c.f = f;
  unsigned int x = c.i;
  return (unsigned short)((x + 0x7fffu + ((x >> 16) & 1u)) >> 16);  // RNE
}
__device__ __forceinline__ float bfu2f(unsigned short u){
  union { unsigned int i; float f; } c; c.i = ((unsigned int)u) << 16; return c.f;
}
__device__ __forceinline__ float dsilu(float x){ return x / (1.f + __expf(-x)); }

// ---------- x: fp32 NCHW [b][512][1024] -> bf16 NHWC [b][1024][512] ----------
__global__ __launch_bounds__(256)
void transpose_x_k(const float* __restrict__ x, ushort_t* __restrict__ xc)
{
  __shared__ float tl[64*68];
  const int ci0 = blockIdx.x*64, px0 = blockIdx.y*64, b = blockIdx.z;
  const int t = threadIdx.x;
  {
    const int ci_l = t>>2, pc = (t&3)*16;
    const float* src = x + (size_t)b*524288 + (size_t)(ci0+ci_l)*1024 + px0 + pc;
    float* d = &tl[ci_l*68 + pc];
    *(float4*)(d)    = *(const float4*)(src);
    *(float4*)(d+4)  = *(const float4*)(src+4);
    *(float4*)(d+8)  = *(const float4*)(src+8);
    *(float4*)(d+12) = *(const float4*)(src+12);
  }
  __syncthreads();
  {
    const int px_l = t>>2, cc = (t&3)*16;
    us8 o0, o1;
#pragma unroll
    for (int i = 0; i < 8; i++) o0[i] = f2bfu(tl[(cc+i)*68 + px_l]);
#pragma unroll
    for (int i = 0; i < 8; i++) o1[i] = f2bfu(tl[(cc+8+i)*68 + px_l]);
    ushort_t* dst = xc + (size_t)b*524288 + (size_t)(px0+px_l)*512 + ci0 + cc;
    *(us8*)dst = o0; *(us8*)(dst+8) = o1;
  }
}

// ---------- 4-segment flat fp32 -> bf16 ----------
__global__ __launch_bounds__(256)
void cvt4_k(const float* s0, const float* s1, const float* s2, const float* s3,
            ushort_t* d0, ushort_t* d1, ushort_t* d2, ushort_t* d3,
            int n0, int n1, int n2, int n3)
{
  const int seg = blockIdx.y;
  const float* s = (seg==0?s0:seg==1?s1:seg==2?s2:s3);
  ushort_t* d    = (seg==0?d0:seg==1?d1:seg==2?d2:d3);
  const int n4   = (seg==0?n0:seg==1?n1:seg==2?n2:n3) >> 2;
  for (int i = blockIdx.x*256 + threadIdx.x; i < n4; i += gridDim.x*256){
    const float4 v = *(const float4*)(s + (size_t)i*4);
    ushort4 p; p.x=f2bfu(v.x); p.y=f2bfu(v.y); p.z=f2bfu(v.z); p.w=f2bfu(v.w);
    *(ushort4*)(d + (size_t)i*4) = p;
  }
}

// ---------- mcv1_w reorder + zero-stub init ----------
__global__ __launch_bounds__(256)
void reorder3_k(const float* __restrict__ w, ushort_t* __restrict__ o,
                ushort_t* __restrict__ zb)
{
  const int blk = blockIdx.x;                 // n*256+co
  if (blk == 0 && threadIdx.x < 64) zb[threadIdx.x] = 0;
  const float* src = w + (size_t)blk*2304;
  ushort_t* dst = o + (size_t)blk*2304;
  for (int idx = threadIdx.x; idx < 2304; idx += 256){
    const int ci = idx/9, tap = idx - ci*9;
    dst[tap*256 + ci] = f2bfu(src[idx]);
  }
}

// ---------- MFMA GEMM: D[m=co][n=px] = A[co][k] * B[k][px] per batch ----------
// Tile 64 x NT, 4 waves, BK=64 (8-row x 128B LDS chunks, slot-XOR swizzle).
// BMODE 0: channels-last B | 1: concat-4 | 2: implicit im2col direct from yi (zero-stub OOB)
// EPI 0: BN+SiLU -> bf16 cl | 1: qkv (q/k -> qk [px][512]; v -> vt NCHW) | 2: +res
// EPI 3: BN+SiLU -> fp32 NCHW | 4: raw fp32 partial
template<int BMODE, int EPI, int NT>
__global__ __launch_bounds__(256, 4)
void gemm_k(const ushort_t* __restrict__ A, const int M, const int K, const int kplen,
            const ushort_t* __restrict__ B0, const ushort_t* __restrict__ B1,
            const ushort_t* __restrict__ B2, const ushort_t* __restrict__ B3,
            const int Rb, const long Bbs,
            const float* __restrict__ bnp,
            const float* __restrict__ rw, const float* __restrict__ rh,
            const ushort_t* __restrict__ res, const long res_bs, const int res_rs,
            ushort_t* __restrict__ vtout, const ushort_t* __restrict__ zb,
            void* __restrict__ outp, const long out_bs, const int out_rs)
{
  constexpr int NW = NT/4;          // n-width per wave
  constexpr int NF = NW/16;         // n-fragments per wave
  constexpr int CH = 8 + NT/8;      // total 8-row chunks (A=8, B=NT/8)
  constexpr int CPW = CH/4;         // chunks per wave
  const int m0 = blockIdx.x*64, n0 = blockIdx.y*NT;
  const int bz = blockIdx.z, b = bz & 7, part = bz >> 3;
  const int tid = threadIdx.x, lane = tid & 63, w = tid >> 6;
  const int q = lane >> 4, l15 = lane & 15;
  const int crow8 = lane >> 3, kq8 = lane & 7;
  const int gq8 = kq8 ^ crow8;                  // swizzled global quarter (loader)
  const int r7 = l15 & 7;
  __shared__ __align__(16) ushort_t A_s[64*64];
  __shared__ __align__(16) ushort_t B_s[NT*64];

  f32x4 acc[4][NF];
#pragma unroll
  for (int mi = 0; mi < 4; mi++)
#pragma unroll
    for (int ni = 0; ni < NF; ni++) acc[mi][ni] = (f32x4){0.f,0.f,0.f,0.f};

  const int kbeg = part*kplen, kend_ = kbeg + kplen;
  for (int k0 = kbeg; k0 < kend_; k0 += 64){
    const int kk = k0 + gq8*8;
#pragma unroll
    for (int p = 0; p < CPW; p++){
      const int c = w*CPW + p;
      if (c < 8){
        const int row = c*8 + crow8;
        gld16(A + (size_t)(m0 + row)*K + kk, A_s + c*512);
      } else {
        const int cb = c - 8;
        const int row = cb*8 + crow8;
        const ushort_t* gb;
        if (BMODE == 0){
          gb = B0 + (size_t)b*Bbs + (size_t)(n0 + row)*Rb + kk;
        } else if (BMODE == 1){
          const int seg = kk >> 8;
          const ushort_t* sb = (seg==0?B0:seg==1?B1:seg==2?B2:B3);
          const int sstr = (seg < 2) ? 512 : 256;
          const long sbs = (seg < 2) ? 524288L : 262144L;
          gb = sb + (size_t)b*sbs + (size_t)(n0 + row)*sstr + (kk & 255);
        } else {
          const int tap = k0 >> 8;
          const int ci = (k0 & 255) + gq8*8;
          const int oy = tap/3 - 1, ox = tap - (tap/3)*3 - 1;
          const int px = n0 + row;
          const int yy = (px >> 5) + oy, xx = (px & 31) + ox;
          const bool vld = ((unsigned)yy < 32u) && ((unsigned)xx < 32u);
          gb = vld ? (B0 + (size_t)b*Bbs + (size_t)(yy*32 + xx)*Rb + ci) : zb;
        }
        gld16(gb, B_s + cb*512);
      }
    }
    __syncthreads();
#pragma unroll
    for (int ks = 0; ks < 2; ks++){
      const int slot = (ks*4 + q) ^ r7;
      bf16x8 af[4], bfr[NF];
#pragma unroll
      for (int mi = 0; mi < 4; mi++)
        af[mi] = __builtin_bit_cast(bf16x8, *(const us8*)&A_s[(mi*16 + l15)*64 + slot*8]);
#pragma unroll
      for (int ni = 0; ni < NF; ni++)
        bfr[ni] = __builtin_bit_cast(bf16x8, *(const us8*)&B_s[(w*NW + ni*16 + l15)*64 + slot*8]);
#pragma unroll
      for (int mi = 0; mi < 4; mi++)
#pragma unroll
        for (int ni = 0; ni < NF; ni++)
          acc[mi][ni] = mfma16(af[mi], bfr[ni], acc[mi][ni]);
    }
    __syncthreads();
  }

  // ---- epilogue ----
  const int n_w = n0 + w*NW;
#pragma unroll
  for (int mi = 0; mi < 4; mi++){
    const int mb = m0 + mi*16 + q*4;      // 4 consecutive co
    float sc[4], off[4];
    if (EPI != 1 && EPI != 4){
      const float4 g  = *(const float4*)(bnp + mb);
      const float4 be = *(const float4*)(bnp + M + mb);
      const float4 mu = *(const float4*)(bnp + 2*M + mb);
      const float4 va = *(const float4*)(bnp + 3*M + mb);
      sc[0] = g.x/sqrtf(va.x+1e-3f); off[0] = be.x - mu.x*sc[0];
      sc[1] = g.y/sqrtf(va.y+1e-3f); off[1] = be.y - mu.y*sc[1];
      sc[2] = g.z/sqrtf(va.z+1e-3f); off[2] = be.z - mu.z*sc[2];
      sc[3] = g.w/sqrtf(va.w+1e-3f); off[3] = be.w - mu.w*sc[3];
    }
    const int region = mb >> 8;
#pragma unroll
    for (int ni = 0; ni < NF; ni++){
      const int n_g = n_w + ni*16 + l15;
      f32x4 v = acc[mi][ni];
      if (EPI == 4){
        *(float4*)((float*)outp + ((size_t)(part*8 + b)*1024 + n_g)*256 + mb) =
            (float4){v[0], v[1], v[2], v[3]};
        continue;
      }
      float o[4];
#pragma unroll
      for (int r = 0; r < 4; r++){
        float xv = v[r];
        if (EPI == 1){
          if (region == 0) xv *= 0.18033688011112042f;   // 0.125 * log2(e)
          else if (region == 1){
            const int c64 = mb + r - 256;
            xv += rw[c64*32 + (n_g & 31)] + rh[c64*32 + (n_g >> 5)];
          }
        } else {
          xv = dsilu(xv*sc[r] + off[r]);
          if (EPI == 2)
            xv += bfu2f(res[(size_t)b*res_bs + (size_t)n_g*res_rs + mb + r]);
        }
        o[r] = xv;
      }
      if (EPI == 3){
        float* of = (float*)outp + (size_t)b*out_bs;
#pragma unroll
        for (int r = 0; r < 4; r++) of[(size_t)(mb + r)*1024 + n_g] = o[r];
      } else if (EPI == 1 && region == 2){
        // V -> transposed NCHW vt buffer [b][ch][px]
#pragma unroll
        for (int r = 0; r < 4; r++)
          vtout[(size_t)b*262144 + (size_t)(mb + r - 512)*1024 + n_g] = f2bfu(o[r]);
      } else {
        ushort4 pk; pk.x=f2bfu(o[0]); pk.y=f2bfu(o[1]); pk.z=f2bfu(o[2]); pk.w=f2bfu(o[3]);
        *(ushort4*)((ushort_t*)outp + (size_t)b*out_bs + (size_t)n_g*out_rs + mb) = pk;
      }
    }
  }
}

// ---------- split-K reduce (2 parts) + BN + SiLU -> bf16 channels-last ----------
__global__ __launch_bounds__(256)
void reduce3_k(const float* __restrict__ pbuf, const float* __restrict__ bnp,
               ushort_t* __restrict__ out)
{
  const int idx = blockIdx.x*256 + threadIdx.x;   // (b,px,co4), co4 fastest
  const int co = (idx & 63)*4;
  const size_t e = (size_t)idx*4;
  float4 a = *(const float4*)(pbuf + e);
  const float4 c = *(const float4*)(pbuf + 2097152 + e);
  a.x += c.x; a.y += c.y; a.z += c.z; a.w += c.w;
  const float4 g  = *(const float4*)(bnp + co);
  const float4 be = *(const float4*)(bnp + 256 + co);
  const float4 mu = *(const float4*)(bnp + 512 + co);
  const float4 va = *(const float4*)(bnp + 768 + co);
  float s0 = g.x/sqrtf(va.x+1e-3f), s1 = g.y/sqrtf(va.y+1e-3f);
  float s2 = g.z/sqrtf(va.z+1e-3f), s3 = g.w/sqrtf(va.w+1e-3f);
  ushort4 pk;
  pk.x = f2bfu(dsilu((a.x - mu.x)*s0 + be.x));
  pk.y = f2bfu(dsilu((a.y - mu.y)*s1 + be.y));
  pk.z = f2bfu(dsilu((a.z - mu.z)*s2 + be.z));
  pk.w = f2bfu(dsilu((a.w - mu.w)*s3 + be.w));
  *(ushort4*)(out + e) = pk;
}

// ---------- flash attention v3: S^T softmax, exp2 domain, packed P writes ----------
// qk: [b][px][512] (q pre-scaled by 0.125*log2e; k with r added)
// vt: [b][256ch][1024px] NCHW bf16
__global__ __launch_bounds__(256)
void attn_k(const ushort_t* __restrict__ qk, const ushort_t* __restrict__ vt,
            ushort_t* __restrict__ out)
{
  const int it = blockIdx.x, h = blockIdx.y, b = blockIdx.z;
  const int tid = threadIdx.x, lane = tid & 63, w = tid >> 6;
  const int q = lane >> 4, l15 = lane & 15;
  const int i0 = it*64;
  __shared__ __align__(16) ushort_t K_s[2][4096];
  __shared__ __align__(16) ushort_t V_s[2][4096];
  __shared__ __align__(16) ushort_t P_s[4096];

  const ushort_t* qkb = qk + (size_t)b*524288;
  const ushort_t* vtb = vt + (size_t)b*262144 + (size_t)h*1024*64;

  const int srow = lane >> 3;                 // row within 8-row chunk
  const int sgq  = (lane & 7) ^ srow;         // global quarter for LDS slot lane&7
  const int rs7  = l15 & 7;

  bf16x8 qf[2];
  {
    const ushort_t* qr = qkb + (size_t)(i0 + w*16 + l15)*512 + h*64 + q*8;
    qf[0] = __builtin_bit_cast(bf16x8, *(const us8*)qr);
    qf[1] = __builtin_bit_cast(bf16x8, *(const us8*)(qr + 32));
  }
  f32x4 oacc[4];
#pragma unroll
  for (int nd = 0; nd < 4; nd++) oacc[nd] = (f32x4){0.f,0.f,0.f,0.f};
  float m_s = -3e38f, l_s = 0.f;   // per-lane: Q-row i = l15

#define STAGE(JT, BUF) {                                                        \
    const int j0s = (JT)*64;                                                    \
    _Pragma("unroll")                                                           \
    for (int p = 0; p < 2; p++){                                                \
      const int c = w*2 + p;                                                    \
      const int row = c*8 + srow;                                               \
      gld16(qkb + (size_t)(j0s + row)*512 + 256 + h*64 + sgq*8, &K_s[BUF][c*512]); \
      gld16(vtb + (size_t)row*1024 + j0s + sgq*8, &V_s[BUF][c*512]);            \
    }                                                                           \
  }

  STAGE(0, 0);
  int cur = 0;
  for (int jt = 0; jt < 16; jt++){
    __syncthreads();              // buffers[cur] staged; prev bufs free
    if (jt < 15){ STAGE(jt+1, cur^1); }
    // S^T = K Q^T : D[rows j = ni*16+q*4+r][cols i = l15]
    f32x4 sacc[4];
#pragma unroll
    for (int ni = 0; ni < 4; ni++) sacc[ni] = (f32x4){0.f,0.f,0.f,0.f};
#pragma unroll
    for (int ks = 0; ks < 2; ks++){
      const int slot = (ks*4 + q) ^ rs7;
#pragma unroll
      for (int ni = 0; ni < 4; ni++){
        const bf16x8 kf = __builtin_bit_cast(bf16x8,
            *(const us8*)&K_s[cur][(ni*16 + l15)*64 + slot*8]);
        sacc[ni] = mfma16(kf, qf[ks], sacc[ni]);
      }
    }
    // online softmax: lane owns row i=l15, 16 j-values (exp2 domain)
    float mx = sacc[0][0];
#pragma unroll
    for (int ni = 0; ni < 4; ni++)
#pragma unroll
      for (int r = 0; r < 4; r++) mx = fmaxf(mx, sacc[ni][r]);
    mx = fmaxf(mx, __shfl_xor(mx, 16));
    mx = fmaxf(mx, __shfl_xor(mx, 32));
    const float mnew = fmaxf(m_s, mx);
    const float alpha = EXP2F(m_s - mnew);
    m_s = mnew;
    float p[4][4];
    float ps = 0.f;
#pragma unroll
    for (int ni = 0; ni < 4; ni++)
#pragma unroll
      for (int r = 0; r < 4; r++){ p[ni][r] = EXP2F(sacc[ni][r] - mnew); ps += p[ni][r]; }
    ps += __shfl_xor(ps, 16);
    ps += __shfl_xor(ps, 32);
    l_s = l_s*alpha + ps;
    // O-rescale: O rows are i = q*4+r -> fetch alpha from lane q*4+r
#pragma unroll
    for (int r = 0; r < 4; r++){
      const float a_r = __shfl(alpha, q*4 + r);
#pragma unroll
      for (int nd = 0; nd < 4; nd++) oacc[nd][r] *= a_r;
    }
    // write P[i=row][j], packed 4x bf16 (j = ni*16 + q*4 + 0..3)
    {
      const int prow = w*16 + l15;
#pragma unroll
      for (int ni = 0; ni < 4; ni++){
        const int qtr = ni*2 + (q>>1);
        us4 pk = { f2bfu(p[ni][0]), f2bfu(p[ni][1]), f2bfu(p[ni][2]), f2bfu(p[ni][3]) };
        *(us4*)&P_s[prow*64 + ((qtr ^ rs7)<<3) + ((q&1)<<2)] = pk;
      }
    }
    // O += P V (intra-wave P dependency)
#pragma unroll
    for (int ks = 0; ks < 2; ks++){
      const int slot = (ks*4 + q) ^ rs7;
      const bf16x8 pa = __builtin_bit_cast(bf16x8,
          *(const us8*)&P_s[(w*16 + l15)*64 + slot*8]);
#pragma unroll
      for (int nd = 0; nd < 4; nd++){
        const bf16x8 vb = __builtin_bit_cast(bf16x8,
            *(const us8*)&V_s[cur][(nd*16 + l15)*64 + slot*8]);
        oacc[nd] = mfma16(pa, vb, oacc[nd]);
      }
    }
    cur ^= 1;
  }
#undef STAGE
  ushort_t* ob = out + (size_t)b*262144;
#pragma unroll
  for (int r = 0; r < 4; r++){
    const float rinv = 1.f / __shfl(l_s, q*4 + r);
    const size_t rowo = (size_t)(i0 + w*16 + q*4 + r)*256 + h*64 + l15;
#pragma unroll
    for (int nd = 0; nd < 4; nd++)
      ob[rowo + nd*16] = f2bfu(oacc[nd][r]*rinv);
  }
}

// ---------- host ----------
extern "C" void kernel_launch(void* const* d_in, const int* in_sizes, int n_in,
                              void* d_out, int out_size, void* d_ws, size_t ws_size,
                              hipStream_t stream)
{
  const float* x       = (const float*)d_in[0];
  const float* cv1_w   = (const float*)d_in[1];
  const float* cv1_bn  = (const float*)d_in[2];
  const float* cv2_w   = (const float*)d_in[3];
  const float* cv2_bn  = (const float*)d_in[4];
  const float* mcv1_w  = (const float*)d_in[5];
  const float* mcv1_bn = (const float*)d_in[6];
  const float* mqkv_w  = (const float*)d_in[7];
  const float* mrw     = (const float*)d_in[8];
  const float* mrh     = (const float*)d_in[9];
  const float* mcv2_w  = (const float*)d_in[10];
  const float* mcv2_bn = (const float*)d_in[11];

  ushort_t* uw = (ushort_t*)d_ws;
  ushort_t* x_cl    = uw;                  // 4,194,304
  ushort_t* t_cl    = x_cl    + 4194304;   // 4,194,304
  ushort_t* wb_cv1  = t_cl    + 4194304;   //   262,144
  ushort_t* wb_cv2  = wb_cv1  + 262144;    //   524,288
  ushort_t* wb_qkv  = wb_cv2  + 524288;    //   393,216
  ushort_t* wb_mcv2 = wb_qkv  + 393216;    //   131,072
  ushort_t* wb_mcv1 = wb_mcv2 + 131072;    // 1,179,648
  ushort_t* z1_cl   = wb_mcv1 + 1179648;   // 2,097,152
  ushort_t* qk_cl   = z1_cl   + 2097152;   // 4,194,304  [b][px][512]
  ushort_t* vt_b    = qk_cl   + 4194304;   // 2,097,152  [b][256][1024]
  ushort_t* att_cl  = vt_b    + 2097152;   // 2,097,152
  ushort_t* y2_cl   = att_cl  + 2097152;   // 2,097,152
  ushort_t* y3_cl   = y2_cl   + 2097152;   // 2,097,152
  float*    part_f  = (float*)(y3_cl + 2097152);  // 4,194,304 floats (16 MB)
  ushort_t* zbuf    = (ushort_t*)(part_f + 4194304); // 64 zeros

  const dim3 blk(256);

  transpose_x_k<<<dim3(8,16,8), blk, 0, stream>>>(x, x_cl);
  cvt4_k<<<dim3(256,4), blk, 0, stream>>>(cv1_w, cv2_w, mqkv_w, mcv2_w,
                                          wb_cv1, wb_cv2, wb_qkv, wb_mcv2,
                                          262144, 524288, 393216, 131072);
  reorder3_k<<<dim3(512), blk, 0, stream>>>(mcv1_w, wb_mcv1, zbuf);

  // cv1: [512 co][512 ci] x x_cl -> t_cl (512 blocks)
  gemm_k<0,0,128><<<dim3(8,8,8), blk, 0, stream>>>(
      wb_cv1, 512, 512, 512, x_cl, nullptr, nullptr, nullptr, 512, 524288L,
      cv1_bn, nullptr, nullptr, nullptr, 0, 0, nullptr, nullptr, t_cl, 524288L, 512);

  const ushort_t* yi = t_cl + 256;  long yi_bs = 524288; int yi_rs = 512;
  ushort_t* youts[2] = { y2_cl, y3_cl };
  for (int i = 0; i < 2; i++){
    // conv3x3 implicit-im2col directly from yi, split-K x2 (512 blocks)
    gemm_k<2,4,128><<<dim3(4,8,16), blk, 0, stream>>>(
        wb_mcv1 + (size_t)i*589824, 256, 2304, 1152, yi, nullptr, nullptr, nullptr,
        yi_rs, yi_bs,
        nullptr, nullptr, nullptr, nullptr, 0, 0, nullptr, zbuf, part_f, 0, 0);
    reduce3_k<<<dim3(2048), blk, 0, stream>>>(part_f, mcv1_bn + i*1024, z1_cl);
    // qkv (768 blocks): q/k -> qk_cl [px][512], v -> vt_b NCHW
    gemm_k<0,1,128><<<dim3(12,8,8), blk, 0, stream>>>(
        wb_qkv + (size_t)i*196608, 768, 256, 256, z1_cl, nullptr, nullptr, nullptr, 256, 262144L,
        nullptr, mrw + i*8192, mrh + i*8192, nullptr, 0, 0, vt_b, nullptr, qk_cl, 524288L, 512);
    attn_k<<<dim3(16,4,8), blk, 0, stream>>>(qk_cl, vt_b, att_cl);
    // mcv2 + residual (512 blocks, 64x64 tile)
    gemm_k<0,2,64><<<dim3(4,16,8), blk, 0, stream>>>(
        wb_mcv2 + (size_t)i*65536, 256, 256, 256, att_cl, nullptr, nullptr, nullptr, 256, 262144L,
        mcv2_bn + i*1024, nullptr, nullptr, yi, yi_bs, yi_rs, nullptr, nullptr,
        youts[i], 262144L, 256);
    yi = youts[i]; yi_bs = 262144; yi_rs = 256;
  }

  // concat [y0|y1|y2|y3] 1024ch -> 512, fp32 NCHW out (512 blocks)
  gemm_k<1,3,128><<<dim3(8,8,8), blk, 0, stream>>>(
      wb_cv2, 512, 1024, 1024, t_cl, t_cl + 256, y2_cl, y3_cl, 0, 0,
      cv2_bn, nullptr, nullptr, nullptr, 0, 0, nullptr, nullptr, (float*)d_out, 524288L, 0);
}

// Round 9
// 295.289 us; speedup vs baseline: 10.1300x; 1.0305x over previous
//
#include <hip/hip_runtime.h>
#include <hip/hip_bf16.h>

typedef unsigned short ushort_t;
typedef __bf16 bf16x8 __attribute__((ext_vector_type(8)));
typedef float f32x4 __attribute__((ext_vector_type(4)));
typedef unsigned short us8 __attribute__((ext_vector_type(8)));
typedef unsigned int u32;

#define AS1 __attribute__((address_space(1)))
#define AS3 __attribute__((address_space(3)))

#if __has_builtin(__builtin_amdgcn_exp2f)
#define EXP2F __builtin_amdgcn_exp2f
#else
#define EXP2F exp2f
#endif

__device__ __forceinline__ void gld16(const void* g, void* l){
  __builtin_amdgcn_global_load_lds((AS1 void*)(void*)g, (AS3 void*)l, 16, 0, 0);
}
__device__ __forceinline__ f32x4 mfma16(bf16x8 a, bf16x8 b, f32x4 c){
  return __builtin_amdgcn_mfma_f32_16x16x32_bf16(a, b, c, 0, 0, 0);
}
__device__ __forceinline__ unsigned short f2bfu(float f){
  union { float f; unsigned int i; } c; c.f = f;
  unsigned int x = c.i;
  return (unsigned short)((x + 0x7fffu + ((x >> 16) & 1u)) >> 16);  // RNE
}
__device__ __forceinline__ float bfu2f(unsigned short u){
  union { unsigned int i; float f; } c; c.i = ((unsigned int)u) << 16; return c.f;
}
__device__ __forceinline__ float dsilu(float x){ return x / (1.f + __expf(-x)); }
// pack two fp32 -> two bf16 (truncation), 1 v_perm_b32
__device__ __forceinline__ u32 pack_trunc(float a, float b){
  union { float f; u32 u; } ca, cb; ca.f = a; cb.f = b;
#if __has_builtin(__builtin_amdgcn_perm)
  return __builtin_amdgcn_perm(cb.u, ca.u, 0x07060302u);
#else
  return (cb.u & 0xFFFF0000u) | (ca.u >> 16);
#endif
}

// ---------- fused prep: transpose_x (0..1023) | cvt4 (1024..2047) | reorder3 (2048..2559)
__global__ __launch_bounds__(256)
void prep_k(const float* __restrict__ x, ushort_t* __restrict__ xc,
            const float* __restrict__ s0, const float* __restrict__ s1,
            const float* __restrict__ s2, const float* __restrict__ s3,
            ushort_t* __restrict__ d0, ushort_t* __restrict__ d1,
            ushort_t* __restrict__ d2, ushort_t* __restrict__ d3,
            const float* __restrict__ w3, ushort_t* __restrict__ o3,
            ushort_t* __restrict__ zb)
{
  __shared__ float tl[64*68];
  const int bx = blockIdx.x, t = threadIdx.x;
  if (bx < 1024){
    const int b = bx >> 7, ci0 = (bx & 7)*64, px0 = ((bx >> 3) & 15)*64;
    {
      const int ci_l = t>>2, pc = (t&3)*16;
      const float* src = x + (size_t)b*524288 + (size_t)(ci0+ci_l)*1024 + px0 + pc;
      float* d = &tl[ci_l*68 + pc];
      *(float4*)(d)    = *(const float4*)(src);
      *(float4*)(d+4)  = *(const float4*)(src+4);
      *(float4*)(d+8)  = *(const float4*)(src+8);
      *(float4*)(d+12) = *(const float4*)(src+12);
    }
    __syncthreads();
    {
      const int px_l = t>>2, cc = (t&3)*16;
      us8 o0, o1;
#pragma unroll
      for (int i = 0; i < 8; i++) o0[i] = f2bfu(tl[(cc+i)*68 + px_l]);
#pragma unroll
      for (int i = 0; i < 8; i++) o1[i] = f2bfu(tl[(cc+8+i)*68 + px_l]);
      ushort_t* dst = xc + (size_t)b*524288 + (size_t)(px0+px_l)*512 + ci0 + cc;
      *(us8*)dst = o0; *(us8*)(dst+8) = o1;
    }
  } else if (bx < 2048){
    const int bb = bx - 1024;
    const int seg = bb >> 8, blk = bb & 255;
    const float* s = (seg==0?s0:seg==1?s1:seg==2?s2:s3);
    ushort_t* d    = (seg==0?d0:seg==1?d1:seg==2?d2:d3);
    const int n4   = (seg==0?262144:seg==1?524288:seg==2?393216:131072) >> 2;
    for (int i = blk*256 + t; i < n4; i += 256*256){
      const float4 v = *(const float4*)(s + (size_t)i*4);
      ushort4 p; p.x=f2bfu(v.x); p.y=f2bfu(v.y); p.z=f2bfu(v.z); p.w=f2bfu(v.w);
      *(ushort4*)(d + (size_t)i*4) = p;
    }
  } else {
    const int blk = bx - 2048;
    if (blk == 0 && t < 64) zb[t] = 0;
    const float* src = w3 + (size_t)blk*2304;
    ushort_t* dst = o3 + (size_t)blk*2304;
    for (int idx = t; idx < 2304; idx += 256){
      const int ci = idx/9, tap = idx - ci*9;
      dst[tap*256 + ci] = f2bfu(src[idx]);
    }
  }
}

// ---------- MFMA GEMM (unchanged from R8) ----------
template<int BMODE, int EPI, int NT>
__global__ __launch_bounds__(256, 4)
void gemm_k(const ushort_t* __restrict__ A, const int M, const int K, const int kplen,
            const ushort_t* __restrict__ B0, const ushort_t* __restrict__ B1,
            const ushort_t* __restrict__ B2, const ushort_t* __restrict__ B3,
            const int Rb, const long Bbs,
            const float* __restrict__ bnp,
            const float* __restrict__ rw, const float* __restrict__ rh,
            const ushort_t* __restrict__ res, const long res_bs, const int res_rs,
            ushort_t* __restrict__ vtout, const ushort_t* __restrict__ zb,
            void* __restrict__ outp, const long out_bs, const int out_rs)
{
  constexpr int NW = NT/4;
  constexpr int NF = NW/16;
  constexpr int CH = 8 + NT/8;
  constexpr int CPW = CH/4;
  const int m0 = blockIdx.x*64, n0 = blockIdx.y*NT;
  const int bz = blockIdx.z, b = bz & 7, part = bz >> 3;
  const int tid = threadIdx.x, lane = tid & 63, w = tid >> 6;
  const int q = lane >> 4, l15 = lane & 15;
  const int crow8 = lane >> 3, kq8 = lane & 7;
  const int gq8 = kq8 ^ crow8;
  const int r7 = l15 & 7;
  __shared__ __align__(16) ushort_t A_s[64*64];
  __shared__ __align__(16) ushort_t B_s[NT*64];

  f32x4 acc[4][NF];
#pragma unroll
  for (int mi = 0; mi < 4; mi++)
#pragma unroll
    for (int ni = 0; ni < NF; ni++) acc[mi][ni] = (f32x4){0.f,0.f,0.f,0.f};

  const int kbeg = part*kplen, kend_ = kbeg + kplen;
  for (int k0 = kbeg; k0 < kend_; k0 += 64){
    const int kk = k0 + gq8*8;
#pragma unroll
    for (int p = 0; p < CPW; p++){
      const int c = w*CPW + p;
      if (c < 8){
        const int row = c*8 + crow8;
        gld16(A + (size_t)(m0 + row)*K + kk, A_s + c*512);
      } else {
        const int cb = c - 8;
        const int row = cb*8 + crow8;
        const ushort_t* gb;
        if (BMODE == 0){
          gb = B0 + (size_t)b*Bbs + (size_t)(n0 + row)*Rb + kk;
        } else if (BMODE == 1){
          const int seg = kk >> 8;
          const ushort_t* sb = (seg==0?B0:seg==1?B1:seg==2?B2:B3);
          const int sstr = (seg < 2) ? 512 : 256;
          const long sbs = (seg < 2) ? 524288L : 262144L;
          gb = sb + (size_t)b*sbs + (size_t)(n0 + row)*sstr + (kk & 255);
        } else {
          const int tap = k0 >> 8;
          const int ci = (k0 & 255) + gq8*8;
          const int oy = tap/3 - 1, ox = tap - (tap/3)*3 - 1;
          const int px = n0 + row;
          const int yy = (px >> 5) + oy, xx = (px & 31) + ox;
          const bool vld = ((unsigned)yy < 32u) && ((unsigned)xx < 32u);
          gb = vld ? (B0 + (size_t)b*Bbs + (size_t)(yy*32 + xx)*Rb + ci) : zb;
        }
        gld16(gb, B_s + cb*512);
      }
    }
    __syncthreads();
#pragma unroll
    for (int ks = 0; ks < 2; ks++){
      const int slot = (ks*4 + q) ^ r7;
      bf16x8 af[4], bfr[NF];
#pragma unroll
      for (int mi = 0; mi < 4; mi++)
        af[mi] = __builtin_bit_cast(bf16x8, *(const us8*)&A_s[(mi*16 + l15)*64 + slot*8]);
#pragma unroll
      for (int ni = 0; ni < NF; ni++)
        bfr[ni] = __builtin_bit_cast(bf16x8, *(const us8*)&B_s[(w*NW + ni*16 + l15)*64 + slot*8]);
#pragma unroll
      for (int mi = 0; mi < 4; mi++)
#pragma unroll
        for (int ni = 0; ni < NF; ni++)
          acc[mi][ni] = mfma16(af[mi], bfr[ni], acc[mi][ni]);
    }
    __syncthreads();
  }

  const int n_w = n0 + w*NW;
#pragma unroll
  for (int mi = 0; mi < 4; mi++){
    const int mb = m0 + mi*16 + q*4;
    float sc[4], off[4];
    if (EPI != 1 && EPI != 4){
      const float4 g  = *(const float4*)(bnp + mb);
      const float4 be = *(const float4*)(bnp + M + mb);
      const float4 mu = *(const float4*)(bnp + 2*M + mb);
      const float4 va = *(const float4*)(bnp + 3*M + mb);
      sc[0] = g.x/sqrtf(va.x+1e-3f); off[0] = be.x - mu.x*sc[0];
      sc[1] = g.y/sqrtf(va.y+1e-3f); off[1] = be.y - mu.y*sc[1];
      sc[2] = g.z/sqrtf(va.z+1e-3f); off[2] = be.z - mu.z*sc[2];
      sc[3] = g.w/sqrtf(va.w+1e-3f); off[3] = be.w - mu.w*sc[3];
    }
    const int region = mb >> 8;
#pragma unroll
    for (int ni = 0; ni < NF; ni++){
      const int n_g = n_w + ni*16 + l15;
      f32x4 v = acc[mi][ni];
      if (EPI == 4){
        *(float4*)((float*)outp + ((size_t)(part*8 + b)*1024 + n_g)*256 + mb) =
            (float4){v[0], v[1], v[2], v[3]};
        continue;
      }
      float o[4];
#pragma unroll
      for (int r = 0; r < 4; r++){
        float xv = v[r];
        if (EPI == 1){
          if (region == 0) xv *= 0.18033688011112042f;   // 0.125 * log2(e)
          else if (region == 1){
            const int c64 = mb + r - 256;
            xv += rw[c64*32 + (n_g & 31)] + rh[c64*32 + (n_g >> 5)];
          }
        } else {
          xv = dsilu(xv*sc[r] + off[r]);
          if (EPI == 2)
            xv += bfu2f(res[(size_t)b*res_bs + (size_t)n_g*res_rs + mb + r]);
        }
        o[r] = xv;
      }
      if (EPI == 3){
        float* of = (float*)outp + (size_t)b*out_bs;
#pragma unroll
        for (int r = 0; r < 4; r++) of[(size_t)(mb + r)*1024 + n_g] = o[r];
      } else if (EPI == 1 && region == 2){
#pragma unroll
        for (int r = 0; r < 4; r++)
          vtout[(size_t)b*262144 + (size_t)(mb + r - 512)*1024 + n_g] = f2bfu(o[r]);
      } else {
        ushort4 pk; pk.x=f2bfu(o[0]); pk.y=f2bfu(o[1]); pk.z=f2bfu(o[2]); pk.w=f2bfu(o[3]);
        *(ushort4*)((ushort_t*)outp + (size_t)b*out_bs + (size_t)n_g*out_rs + mb) = pk;
      }
    }
  }
}

// ---------- split-K reduce (unchanged) ----------
__global__ __launch_bounds__(256)
void reduce3_k(const float* __restrict__ pbuf, const float* __restrict__ bnp,
               ushort_t* __restrict__ out)
{
  const int idx = blockIdx.x*256 + threadIdx.x;
  const int co = (idx & 63)*4;
  const size_t e = (size_t)idx*4;
  float4 a = *(const float4*)(pbuf + e);
  const float4 c = *(const float4*)(pbuf + 2097152 + e);
  a.x += c.x; a.y += c.y; a.z += c.z; a.w += c.w;
  const float4 g  = *(const float4*)(bnp + co);
  const float4 be = *(const float4*)(bnp + 256 + co);
  const float4 mu = *(const float4*)(bnp + 512 + co);
  const float4 va = *(const float4*)(bnp + 768 + co);
  float s0 = g.x/sqrtf(va.x+1e-3f), s1 = g.y/sqrtf(va.y+1e-3f);
  float s2 = g.z/sqrtf(va.z+1e-3f), s3 = g.w/sqrtf(va.w+1e-3f);
  ushort4 pk;
  pk.x = f2bfu(dsilu((a.x - mu.x)*s0 + be.x));
  pk.y = f2bfu(dsilu((a.y - mu.y)*s1 + be.y));
  pk.z = f2bfu(dsilu((a.z - mu.z)*s2 + be.z));
  pk.w = f2bfu(dsilu((a.w - mu.w)*s3 + be.w));
  *(ushort4*)(out + e) = pk;
}

// ---------- flash attention v4: BJ=128, S^T softmax, perm-packed P ----------
// qk: [b][px][512] (q pre-scaled by 0.125*log2e; k with r added)
// vt: [b][256ch][1024px] NCHW bf16
__global__ __launch_bounds__(256)
void attn_k(const ushort_t* __restrict__ qk, const ushort_t* __restrict__ vt,
            ushort_t* __restrict__ out)
{
  const int it = blockIdx.x, h = blockIdx.y, b = blockIdx.z;
  const int tid = threadIdx.x, lane = tid & 63, w = tid >> 6;
  const int q = lane >> 4, l15 = lane & 15;
  const int i0 = it*64;
  __shared__ __align__(16) ushort_t K_s[2][8192];   // 128 j-rows x 64 d (8 slots)
  __shared__ __align__(16) ushort_t V_s[2][8192];   // 64 d-rows x 128 j (16 slots)
  __shared__ __align__(16) ushort_t P_s[8192];      // 64 i-rows x 128 j (16 slots)

  const ushort_t* qkb = qk + (size_t)b*524288;
  const ushort_t* vtb = vt + (size_t)b*262144 + (size_t)h*65536;

  const int k_row8 = lane >> 3;            // K: row within 8-row chunk
  const int k_gq   = (lane & 7) ^ k_row8;  // K: global quarter for phys slot lane&7
  const int v_row4 = lane >> 4;            // V: row within 4-row chunk
  const int v_s16  = lane & 15;            // V: phys slot
  const int rs7    = l15 & 7;

  bf16x8 qf[2];
  {
    const ushort_t* qr = qkb + (size_t)(i0 + w*16 + l15)*512 + h*64 + q*8;
    qf[0] = __builtin_bit_cast(bf16x8, *(const us8*)qr);
    qf[1] = __builtin_bit_cast(bf16x8, *(const us8*)(qr + 32));
  }
  f32x4 oacc[4];
#pragma unroll
  for (int nd = 0; nd < 4; nd++) oacc[nd] = (f32x4){0.f,0.f,0.f,0.f};
  float m_s = -3e38f, l_s = 0.f;   // per-lane: Q-row i = w*16 + l15

#define STAGE(JT, BUF) {                                                        \
    const int j0s = (JT)*128;                                                   \
    _Pragma("unroll")                                                           \
    for (int p = 0; p < 4; p++){                                                \
      const int c = w*4 + p;                                                    \
      const int krow = c*8 + k_row8;                                            \
      gld16(qkb + (size_t)(j0s + krow)*512 + 256 + h*64 + k_gq*8, &K_s[BUF][c*512]); \
      const int vrow = c*4 + v_row4;                                            \
      const int vg = v_s16 ^ (vrow & 15);                                       \
      gld16(vtb + (size_t)vrow*1024 + j0s + vg*8, &V_s[BUF][c*512]);            \
    }                                                                           \
  }

  STAGE(0, 0);
  int cur = 0;
  for (int jt = 0; jt < 8; jt++){
    __syncthreads();
    if (jt < 7){ STAGE(jt+1, cur^1); }
    // S^T = K Q^T : rows j (8 frag-groups), cols i = l15
    f32x4 sacc[8];
#pragma unroll
    for (int ni = 0; ni < 8; ni++) sacc[ni] = (f32x4){0.f,0.f,0.f,0.f};
#pragma unroll
    for (int ks = 0; ks < 2; ks++){
      const int slot = (ks*4 + q) ^ rs7;
#pragma unroll
      for (int ni = 0; ni < 8; ni++){
        const bf16x8 kf = __builtin_bit_cast(bf16x8,
            *(const us8*)&K_s[cur][(ni*16 + l15)*64 + slot*8]);
        sacc[ni] = mfma16(kf, qf[ks], sacc[ni]);
      }
    }
    // online softmax (exp2 domain); lane owns 32 j-values of row i
    float mx = sacc[0][0];
#pragma unroll
    for (int ni = 0; ni < 8; ni++)
#pragma unroll
      for (int r = 0; r < 4; r++) mx = fmaxf(mx, sacc[ni][r]);
    mx = fmaxf(mx, __shfl_xor(mx, 16));
    mx = fmaxf(mx, __shfl_xor(mx, 32));
    const float mnew = fmaxf(m_s, mx);
    const float alpha = EXP2F(m_s - mnew);
    m_s = mnew;
    float p[8][4];
    float ps = 0.f;
#pragma unroll
    for (int ni = 0; ni < 8; ni++)
#pragma unroll
      for (int r = 0; r < 4; r++){ p[ni][r] = EXP2F(sacc[ni][r] - mnew); ps += p[ni][r]; }
    ps += __shfl_xor(ps, 16);
    ps += __shfl_xor(ps, 32);
    l_s = l_s*alpha + ps;
#pragma unroll
    for (int r = 0; r < 4; r++){
      const float a_r = __shfl(alpha, q*4 + r);
#pragma unroll
      for (int nd = 0; nd < 4; nd++) oacc[nd][r] *= a_r;
    }
    // write P[i][j]: per ni 4 consecutive j -> one 8B write, trunc-packed
    {
      const int prow = w*16 + l15;
#pragma unroll
      for (int ni = 0; ni < 8; ni++){
        uint2 pk;
        pk.x = pack_trunc(p[ni][0], p[ni][1]);
        pk.y = pack_trunc(p[ni][2], p[ni][3]);
        const int phys = (ni*2 + (q>>1)) ^ l15;
        *(uint2*)&P_s[prow*128 + phys*8 + (q&1)*4] = pk;
      }
    }
    // O += P V (K-dim = 128 j, 4 ks steps; intra-wave P dependency)
#pragma unroll
    for (int ks = 0; ks < 4; ks++){
      const int slotp = (ks*4 + q) ^ l15;
      const bf16x8 pa = __builtin_bit_cast(bf16x8,
          *(const us8*)&P_s[(w*16 + l15)*128 + slotp*8]);
#pragma unroll
      for (int nd = 0; nd < 4; nd++){
        const bf16x8 vb = __builtin_bit_cast(bf16x8,
            *(const us8*)&V_s[cur][(nd*16 + l15)*128 + slotp*8]);
        oacc[nd] = mfma16(pa, vb, oacc[nd]);
      }
    }
    cur ^= 1;
  }
#undef STAGE
  ushort_t* ob = out + (size_t)b*262144;
#pragma unroll
  for (int r = 0; r < 4; r++){
    const float rinv = 1.f / __shfl(l_s, q*4 + r);
    const size_t rowo = (size_t)(i0 + w*16 + q*4 + r)*256 + h*64 + l15;
#pragma unroll
    for (int nd = 0; nd < 4; nd++)
      ob[rowo + nd*16] = f2bfu(oacc[nd][r]*rinv);
  }
}

// ---------- host ----------
extern "C" void kernel_launch(void* const* d_in, const int* in_sizes, int n_in,
                              void* d_out, int out_size, void* d_ws, size_t ws_size,
                              hipStream_t stream)
{
  const float* x       = (const float*)d_in[0];
  const float* cv1_w   = (const float*)d_in[1];
  const float* cv1_bn  = (const float*)d_in[2];
  const float* cv2_w   = (const float*)d_in[3];
  const float* cv2_bn  = (const float*)d_in[4];
  const float* mcv1_w  = (const float*)d_in[5];
  const float* mcv1_bn = (const float*)d_in[6];
  const float* mqkv_w  = (const float*)d_in[7];
  const float* mrw     = (const float*)d_in[8];
  const float* mrh     = (const float*)d_in[9];
  const float* mcv2_w  = (const float*)d_in[10];
  const float* mcv2_bn = (const float*)d_in[11];

  ushort_t* uw = (ushort_t*)d_ws;
  ushort_t* x_cl    = uw;                  // 4,194,304
  ushort_t* t_cl    = x_cl    + 4194304;   // 4,194,304
  ushort_t* wb_cv1  = t_cl    + 4194304;   //   262,144
  ushort_t* wb_cv2  = wb_cv1  + 262144;    //   524,288
  ushort_t* wb_qkv  = wb_cv2  + 524288;    //   393,216
  ushort_t* wb_mcv2 = wb_qkv  + 393216;    //   131,072
  ushort_t* wb_mcv1 = wb_mcv2 + 131072;    // 1,179,648
  ushort_t* z1_cl   = wb_mcv1 + 1179648;   // 2,097,152
  ushort_t* qk_cl   = z1_cl   + 2097152;   // 4,194,304  [b][px][512]
  ushort_t* vt_b    = qk_cl   + 4194304;   // 2,097,152  [b][256][1024]
  ushort_t* att_cl  = vt_b    + 2097152;   // 2,097,152
  ushort_t* y2_cl   = att_cl  + 2097152;   // 2,097,152
  ushort_t* y3_cl   = y2_cl   + 2097152;   // 2,097,152
  float*    part_f  = (float*)(y3_cl + 2097152);  // 4,194,304 floats (16 MB)
  ushort_t* zbuf    = (ushort_t*)(part_f + 4194304); // 64 zeros

  const dim3 blk(256);

  prep_k<<<dim3(2560), blk, 0, stream>>>(x, x_cl,
      cv1_w, cv2_w, mqkv_w, mcv2_w, wb_cv1, wb_cv2, wb_qkv, wb_mcv2,
      mcv1_w, wb_mcv1, zbuf);

  // cv1: [512 co][512 ci] x x_cl -> t_cl (512 blocks)
  gemm_k<0,0,128><<<dim3(8,8,8), blk, 0, stream>>>(
      wb_cv1, 512, 512, 512, x_cl, nullptr, nullptr, nullptr, 512, 524288L,
      cv1_bn, nullptr, nullptr, nullptr, 0, 0, nullptr, nullptr, t_cl, 524288L, 512);

  const ushort_t* yi = t_cl + 256;  long yi_bs = 524288; int yi_rs = 512;
  ushort_t* youts[2] = { y2_cl, y3_cl };
  for (int i = 0; i < 2; i++){
    // conv3x3 implicit-im2col directly from yi, split-K x2 (512 blocks)
    gemm_k<2,4,128><<<dim3(4,8,16), blk, 0, stream>>>(
        wb_mcv1 + (size_t)i*589824, 256, 2304, 1152, yi, nullptr, nullptr, nullptr,
        yi_rs, yi_bs,
        nullptr, nullptr, nullptr, nullptr, 0, 0, nullptr, zbuf, part_f, 0, 0);
    reduce3_k<<<dim3(2048), blk, 0, stream>>>(part_f, mcv1_bn + i*1024, z1_cl);
    // qkv (768 blocks): q/k -> qk_cl [px][512], v -> vt_b NCHW
    gemm_k<0,1,128><<<dim3(12,8,8), blk, 0, stream>>>(
        wb_qkv + (size_t)i*196608, 768, 256, 256, z1_cl, nullptr, nullptr, nullptr, 256, 262144L,
        nullptr, mrw + i*8192, mrh + i*8192, nullptr, 0, 0, vt_b, nullptr, qk_cl, 524288L, 512);
    attn_k<<<dim3(16,4,8), blk, 0, stream>>>(qk_cl, vt_b, att_cl);
    // mcv2 + residual (512 blocks, 64x64 tile)
    gemm_k<0,2,64><<<dim3(4,16,8), blk, 0, stream>>>(
        wb_mcv2 + (size_t)i*65536, 256, 256, 256, att_cl, nullptr, nullptr, nullptr, 256, 262144L,
        mcv2_bn + i*1024, nullptr, nullptr, yi, yi_bs, yi_rs, nullptr, nullptr,
        youts[i], 262144L, 256);
    yi = youts[i]; yi_bs = 262144; yi_rs = 256;
  }

  // concat [y0|y1|y2|y3] 1024ch -> 512, fp32 NCHW out (512 blocks)
  gemm_k<1,3,128><<<dim3(8,8,8), blk, 0, stream>>>(
      wb_cv2, 512, 1024, 1024, t_cl, t_cl + 256, y2_cl, y3_cl, 0, 0,
      cv2_bn, nullptr, nullptr, nullptr, 0, 0, nullptr, nullptr, (float*)d_out, 524288L, 0);
}

// Round 10
// 287.623 us; speedup vs baseline: 10.4000x; 1.0267x over previous
//
#include <hip/hip_runtime.h>
#include <hip/hip_bf16.h>

typedef unsigned short ushort_t;
typedef __bf16 bf16x8 __attribute__((ext_vector_type(8)));
typedef float f32x4 __attribute__((ext_vector_type(4)));
typedef unsigned short us8 __attribute__((ext_vector_type(8)));
typedef unsigned int u32;

#define AS1 __attribute__((address_space(1)))
#define AS3 __attribute__((address_space(3)))

#if __has_builtin(__builtin_amdgcn_exp2f)
#define EXP2F __builtin_amdgcn_exp2f
#else
#define EXP2F exp2f
#endif

__device__ __forceinline__ void gld16(const void* g, void* l){
  __builtin_amdgcn_global_load_lds((AS1 void*)(void*)g, (AS3 void*)l, 16, 0, 0);
}
__device__ __forceinline__ f32x4 mfma16(bf16x8 a, bf16x8 b, f32x4 c){
  return __builtin_amdgcn_mfma_f32_16x16x32_bf16(a, b, c, 0, 0, 0);
}
__device__ __forceinline__ unsigned short f2bfu(float f){
  union { float f; unsigned int i; } c; c.f = f;
  unsigned int x = c.i;
  return (unsigned short)((x + 0x7fffu + ((x >> 16) & 1u)) >> 16);  // RNE
}
__device__ __forceinline__ float bfu2f(unsigned short u){
  union { unsigned int i; float f; } c; c.i = ((unsigned int)u) << 16; return c.f;
}
__device__ __forceinline__ float dsilu(float x){ return x / (1.f + __expf(-x)); }
// pack two fp32 -> two bf16 (truncation), 1 v_perm_b32
__device__ __forceinline__ u32 pack_trunc(float a, float b){
  union { float f; u32 u; } ca, cb; ca.f = a; cb.f = b;
#if __has_builtin(__builtin_amdgcn_perm)
  return __builtin_amdgcn_perm(cb.u, ca.u, 0x07060302u);
#else
  return (cb.u & 0xFFFF0000u) | (ca.u >> 16);
#endif
}

// ---------- fused prep: transpose_x (0..1023) | cvt4 (1024..2047) | reorder3 (2048..2559)
__global__ __launch_bounds__(256)
void prep_k(const float* __restrict__ x, ushort_t* __restrict__ xc,
            const float* __restrict__ s0, const float* __restrict__ s1,
            const float* __restrict__ s2, const float* __restrict__ s3,
            ushort_t* __restrict__ d0, ushort_t* __restrict__ d1,
            ushort_t* __restrict__ d2, ushort_t* __restrict__ d3,
            const float* __restrict__ w3, ushort_t* __restrict__ o3,
            ushort_t* __restrict__ zb)
{
  __shared__ float tl[64*68];
  const int bx = blockIdx.x, t = threadIdx.x;
  if (bx < 1024){
    const int b = bx >> 7, ci0 = (bx & 7)*64, px0 = ((bx >> 3) & 15)*64;
    {
      const int ci_l = t>>2, pc = (t&3)*16;
      const float* src = x + (size_t)b*524288 + (size_t)(ci0+ci_l)*1024 + px0 + pc;
      float* d = &tl[ci_l*68 + pc];
      *(float4*)(d)    = *(const float4*)(src);
      *(float4*)(d+4)  = *(const float4*)(src+4);
      *(float4*)(d+8)  = *(const float4*)(src+8);
      *(float4*)(d+12) = *(const float4*)(src+12);
    }
    __syncthreads();
    {
      const int px_l = t>>2, cc = (t&3)*16;
      us8 o0, o1;
#pragma unroll
      for (int i = 0; i < 8; i++) o0[i] = f2bfu(tl[(cc+i)*68 + px_l]);
#pragma unroll
      for (int i = 0; i < 8; i++) o1[i] = f2bfu(tl[(cc+8+i)*68 + px_l]);
      ushort_t* dst = xc + (size_t)b*524288 + (size_t)(px0+px_l)*512 + ci0 + cc;
      *(us8*)dst = o0; *(us8*)(dst+8) = o1;
    }
  } else if (bx < 2048){
    const int bb = bx - 1024;
    const int seg = bb >> 8, blk = bb & 255;
    const float* s = (seg==0?s0:seg==1?s1:seg==2?s2:s3);
    ushort_t* d    = (seg==0?d0:seg==1?d1:seg==2?d2:d3);
    const int n4   = (seg==0?262144:seg==1?524288:seg==2?393216:131072) >> 2;
    for (int i = blk*256 + t; i < n4; i += 256*256){
      const float4 v = *(const float4*)(s + (size_t)i*4);
      ushort4 p; p.x=f2bfu(v.x); p.y=f2bfu(v.y); p.z=f2bfu(v.z); p.w=f2bfu(v.w);
      *(ushort4*)(d + (size_t)i*4) = p;
    }
  } else {
    const int blk = bx - 2048;
    if (blk == 0 && t < 64) zb[t] = 0;
    const float* src = w3 + (size_t)blk*2304;
    ushort_t* dst = o3 + (size_t)blk*2304;
    for (int idx = t; idx < 2304; idx += 256){
      const int ci = idx/9, tap = idx - ci*9;
      dst[tap*256 + ci] = f2bfu(src[idx]);
    }
  }
}

// ---------- MFMA GEMM, double-buffered LDS (one barrier per K-step) ----------
template<int BMODE, int EPI, int NT>
__global__ __launch_bounds__(256, 4)
void gemm_k(const ushort_t* __restrict__ A, const int M, const int K, const int kplen,
            const ushort_t* __restrict__ B0, const ushort_t* __restrict__ B1,
            const ushort_t* __restrict__ B2, const ushort_t* __restrict__ B3,
            const int Rb, const long Bbs,
            const float* __restrict__ bnp,
            const float* __restrict__ rw, const float* __restrict__ rh,
            const ushort_t* __restrict__ res, const long res_bs, const int res_rs,
            ushort_t* __restrict__ vtout, const ushort_t* __restrict__ zb,
            void* __restrict__ outp, const long out_bs, const int out_rs)
{
  constexpr int NW = NT/4;
  constexpr int NF = NW/16;
  constexpr int CH = 8 + NT/8;
  constexpr int CPW = CH/4;
  const int m0 = blockIdx.x*64, n0 = blockIdx.y*NT;
  const int bz = blockIdx.z, b = bz & 7, part = bz >> 3;
  const int tid = threadIdx.x, lane = tid & 63, w = tid >> 6;
  const int q = lane >> 4, l15 = lane & 15;
  const int crow8 = lane >> 3, kq8 = lane & 7;
  const int gq8 = kq8 ^ crow8;
  const int r7 = l15 & 7;
  __shared__ __align__(16) ushort_t A_s[2][4096];
  __shared__ __align__(16) ushort_t B_s[2][NT*64];

  f32x4 acc[4][NF];
#pragma unroll
  for (int mi = 0; mi < 4; mi++)
#pragma unroll
    for (int ni = 0; ni < NF; ni++) acc[mi][ni] = (f32x4){0.f,0.f,0.f,0.f};

  auto stage = [&](int k0, int buf){
    const int kk = k0 + gq8*8;
#pragma unroll
    for (int p = 0; p < CPW; p++){
      const int c = w*CPW + p;
      if (c < 8){
        const int row = c*8 + crow8;
        gld16(A + (size_t)(m0 + row)*K + kk, &A_s[buf][c*512]);
      } else {
        const int cb = c - 8;
        const int row = cb*8 + crow8;
        const ushort_t* gb;
        if (BMODE == 0){
          gb = B0 + (size_t)b*Bbs + (size_t)(n0 + row)*Rb + kk;
        } else if (BMODE == 1){
          const int seg = kk >> 8;
          const ushort_t* sb = (seg==0?B0:seg==1?B1:seg==2?B2:B3);
          const int sstr = (seg < 2) ? 512 : 256;
          const long sbs = (seg < 2) ? 524288L : 262144L;
          gb = sb + (size_t)b*sbs + (size_t)(n0 + row)*sstr + (kk & 255);
        } else {
          const int tap = k0 >> 8;
          const int ci = (k0 & 255) + gq8*8;
          const int oy = tap/3 - 1, ox = tap - (tap/3)*3 - 1;
          const int px = n0 + row;
          const int yy = (px >> 5) + oy, xx = (px & 31) + ox;
          const bool vld = ((unsigned)yy < 32u) && ((unsigned)xx < 32u);
          gb = vld ? (B0 + (size_t)b*Bbs + (size_t)(yy*32 + xx)*Rb + ci) : zb;
        }
        gld16(gb, &B_s[buf][cb*512]);
      }
    }
  };

  const int kbeg = part*kplen, kend_ = kbeg + kplen;
  stage(kbeg, 0);
  int cur = 0;
  for (int k0 = kbeg; k0 < kend_; k0 += 64){
    __syncthreads();                       // buf[cur] landed; prev compute done
    if (k0 + 64 < kend_) stage(k0 + 64, cur ^ 1);
#pragma unroll
    for (int ks = 0; ks < 2; ks++){
      const int slot = (ks*4 + q) ^ r7;
      bf16x8 af[4], bfr[NF];
#pragma unroll
      for (int mi = 0; mi < 4; mi++)
        af[mi] = __builtin_bit_cast(bf16x8, *(const us8*)&A_s[cur][(mi*16 + l15)*64 + slot*8]);
#pragma unroll
      for (int ni = 0; ni < NF; ni++)
        bfr[ni] = __builtin_bit_cast(bf16x8, *(const us8*)&B_s[cur][(w*NW + ni*16 + l15)*64 + slot*8]);
#pragma unroll
      for (int mi = 0; mi < 4; mi++)
#pragma unroll
        for (int ni = 0; ni < NF; ni++)
          acc[mi][ni] = mfma16(af[mi], bfr[ni], acc[mi][ni]);
    }
    cur ^= 1;
  }

  const int n_w = n0 + w*NW;
#pragma unroll
  for (int mi = 0; mi < 4; mi++){
    const int mb = m0 + mi*16 + q*4;
    float sc[4], off[4];
    if (EPI != 1 && EPI != 4){
      const float4 g  = *(const float4*)(bnp + mb);
      const float4 be = *(const float4*)(bnp + M + mb);
      const float4 mu = *(const float4*)(bnp + 2*M + mb);
      const float4 va = *(const float4*)(bnp + 3*M + mb);
      sc[0] = g.x/sqrtf(va.x+1e-3f); off[0] = be.x - mu.x*sc[0];
      sc[1] = g.y/sqrtf(va.y+1e-3f); off[1] = be.y - mu.y*sc[1];
      sc[2] = g.z/sqrtf(va.z+1e-3f); off[2] = be.z - mu.z*sc[2];
      sc[3] = g.w/sqrtf(va.w+1e-3f); off[3] = be.w - mu.w*sc[3];
    }
    const int region = mb >> 8;
#pragma unroll
    for (int ni = 0; ni < NF; ni++){
      const int n_g = n_w + ni*16 + l15;
      f32x4 v = acc[mi][ni];
      if (EPI == 4){
        *(float4*)((float*)outp + ((size_t)(part*8 + b)*1024 + n_g)*256 + mb) =
            (float4){v[0], v[1], v[2], v[3]};
        continue;
      }
      float o[4];
#pragma unroll
      for (int r = 0; r < 4; r++){
        float xv = v[r];
        if (EPI == 1){
          if (region == 0) xv *= 0.18033688011112042f;   // 0.125 * log2(e)
          else if (region == 1){
            const int c64 = mb + r - 256;
            xv += rw[c64*32 + (n_g & 31)] + rh[c64*32 + (n_g >> 5)];
          }
        } else {
          xv = dsilu(xv*sc[r] + off[r]);
          if (EPI == 2)
            xv += bfu2f(res[(size_t)b*res_bs + (size_t)n_g*res_rs + mb + r]);
        }
        o[r] = xv;
      }
      if (EPI == 3){
        float* of = (float*)outp + (size_t)b*out_bs;
#pragma unroll
        for (int r = 0; r < 4; r++) of[(size_t)(mb + r)*1024 + n_g] = o[r];
      } else if (EPI == 1 && region == 2){
#pragma unroll
        for (int r = 0; r < 4; r++)
          vtout[(size_t)b*262144 + (size_t)(mb + r - 512)*1024 + n_g] = f2bfu(o[r]);
      } else {
        ushort4 pk; pk.x=f2bfu(o[0]); pk.y=f2bfu(o[1]); pk.z=f2bfu(o[2]); pk.w=f2bfu(o[3]);
        *(ushort4*)((ushort_t*)outp + (size_t)b*out_bs + (size_t)n_g*out_rs + mb) = pk;
      }
    }
  }
}

// ---------- split-K reduce (unchanged) ----------
__global__ __launch_bounds__(256)
void reduce3_k(const float* __restrict__ pbuf, const float* __restrict__ bnp,
               ushort_t* __restrict__ out)
{
  const int idx = blockIdx.x*256 + threadIdx.x;
  const int co = (idx & 63)*4;
  const size_t e = (size_t)idx*4;
  float4 a = *(const float4*)(pbuf + e);
  const float4 c = *(const float4*)(pbuf + 2097152 + e);
  a.x += c.x; a.y += c.y; a.z += c.z; a.w += c.w;
  const float4 g  = *(const float4*)(bnp + co);
  const float4 be = *(const float4*)(bnp + 256 + co);
  const float4 mu = *(const float4*)(bnp + 512 + co);
  const float4 va = *(const float4*)(bnp + 768 + co);
  float s0 = g.x/sqrtf(va.x+1e-3f), s1 = g.y/sqrtf(va.y+1e-3f);
  float s2 = g.z/sqrtf(va.z+1e-3f), s3 = g.w/sqrtf(va.w+1e-3f);
  ushort4 pk;
  pk.x = f2bfu(dsilu((a.x - mu.x)*s0 + be.x));
  pk.y = f2bfu(dsilu((a.y - mu.y)*s1 + be.y));
  pk.z = f2bfu(dsilu((a.z - mu.z)*s2 + be.z));
  pk.w = f2bfu(dsilu((a.w - mu.w)*s3 + be.w));
  *(ushort4*)(out + e) = pk;
}

// ---------- flash attention v5: BJ=128, S^T softmax, l via ones-MFMA ----------
__global__ __launch_bounds__(256)
void attn_k(const ushort_t* __restrict__ qk, const ushort_t* __restrict__ vt,
            ushort_t* __restrict__ out)
{
  const int it = blockIdx.x, h = blockIdx.y, b = blockIdx.z;
  const int tid = threadIdx.x, lane = tid & 63, w = tid >> 6;
  const int q = lane >> 4, l15 = lane & 15;
  const int i0 = it*64;
  __shared__ __align__(16) ushort_t K_s[2][8192];
  __shared__ __align__(16) ushort_t V_s[2][8192];
  __shared__ __align__(16) ushort_t P_s[8192];

  const ushort_t* qkb = qk + (size_t)b*524288;
  const ushort_t* vtb = vt + (size_t)b*262144 + (size_t)h*65536;

  const int k_row8 = lane >> 3;
  const int k_gq   = (lane & 7) ^ k_row8;
  const int v_row4 = lane >> 4;
  const int v_s16  = lane & 15;
  const int rs7    = l15 & 7;

  bf16x8 qf[2];
  {
    const ushort_t* qr = qkb + (size_t)(i0 + w*16 + l15)*512 + h*64 + q*8;
    qf[0] = __builtin_bit_cast(bf16x8, *(const us8*)qr);
    qf[1] = __builtin_bit_cast(bf16x8, *(const us8*)(qr + 32));
  }
  const us8 ones_u = { 0x3F80,0x3F80,0x3F80,0x3F80,0x3F80,0x3F80,0x3F80,0x3F80 };
  const bf16x8 onesf = __builtin_bit_cast(bf16x8, ones_u);

  f32x4 oacc[4];
#pragma unroll
  for (int nd = 0; nd < 4; nd++) oacc[nd] = (f32x4){0.f,0.f,0.f,0.f};
  f32x4 lacc = (f32x4){0.f,0.f,0.f,0.f};
  float m_s = -3e38f;

#define STAGE(JT, BUF) {                                                        \
    const int j0s = (JT)*128;                                                   \
    _Pragma("unroll")                                                           \
    for (int p = 0; p < 4; p++){                                                \
      const int c = w*4 + p;                                                    \
      const int krow = c*8 + k_row8;                                            \
      gld16(qkb + (size_t)(j0s + krow)*512 + 256 + h*64 + k_gq*8, &K_s[BUF][c*512]); \
      const int vrow = c*4 + v_row4;                                            \
      const int vg = v_s16 ^ (vrow & 15);                                       \
      gld16(vtb + (size_t)vrow*1024 + j0s + vg*8, &V_s[BUF][c*512]);            \
    }                                                                           \
  }

  STAGE(0, 0);
  int cur = 0;
  for (int jt = 0; jt < 8; jt++){
    __syncthreads();
    if (jt < 7){ STAGE(jt+1, cur^1); }
    // S^T = K Q^T : rows j (8 frag-groups), cols i = l15
    f32x4 sacc[8];
#pragma unroll
    for (int ni = 0; ni < 8; ni++) sacc[ni] = (f32x4){0.f,0.f,0.f,0.f};
#pragma unroll
    for (int ks = 0; ks < 2; ks++){
      const int slot = (ks*4 + q) ^ rs7;
#pragma unroll
      for (int ni = 0; ni < 8; ni++){
        const bf16x8 kf = __builtin_bit_cast(bf16x8,
            *(const us8*)&K_s[cur][(ni*16 + l15)*64 + slot*8]);
        sacc[ni] = mfma16(kf, qf[ks], sacc[ni]);
      }
    }
    // online softmax (exp2 domain); lane owns 32 j of row i = w*16+l15
    float mx = sacc[0][0];
#pragma unroll
    for (int ni = 0; ni < 8; ni++)
#pragma unroll
      for (int r = 0; r < 4; r++) mx = fmaxf(mx, sacc[ni][r]);
    mx = fmaxf(mx, __shfl_xor(mx, 16));
    mx = fmaxf(mx, __shfl_xor(mx, 32));
    const float mnew = fmaxf(m_s, mx);
    const float alpha = EXP2F(m_s - mnew);
    m_s = mnew;
    float p[8][4];
#pragma unroll
    for (int ni = 0; ni < 8; ni++)
#pragma unroll
      for (int r = 0; r < 4; r++) p[ni][r] = EXP2F(sacc[ni][r] - mnew);
    // rescale O and l (rows i = w*16 + q*4 + r)
#pragma unroll
    for (int r = 0; r < 4; r++){
      const float a_r = __shfl(alpha, q*4 + r);
#pragma unroll
      for (int nd = 0; nd < 4; nd++) oacc[nd][r] *= a_r;
      lacc[r] *= a_r;
    }
    // write P[i][j], trunc-packed, swizzled
    {
      const int prow = w*16 + l15;
#pragma unroll
      for (int ni = 0; ni < 8; ni++){
        uint2 pk;
        pk.x = pack_trunc(p[ni][0], p[ni][1]);
        pk.y = pack_trunc(p[ni][2], p[ni][3]);
        const int phys = (ni*2 + (q>>1)) ^ l15;
        *(uint2*)&P_s[prow*128 + phys*8 + (q&1)*4] = pk;
      }
    }
    // O += P V ; l += P * ones (intra-wave P dependency)
#pragma unroll
    for (int ks = 0; ks < 4; ks++){
      const int slotp = (ks*4 + q) ^ l15;
      const bf16x8 pa = __builtin_bit_cast(bf16x8,
          *(const us8*)&P_s[(w*16 + l15)*128 + slotp*8]);
      lacc = mfma16(pa, onesf, lacc);
#pragma unroll
      for (int nd = 0; nd < 4; nd++){
        const bf16x8 vb = __builtin_bit_cast(bf16x8,
            *(const us8*)&V_s[cur][(nd*16 + l15)*128 + slotp*8]);
        oacc[nd] = mfma16(pa, vb, oacc[nd]);
      }
    }
    cur ^= 1;
  }
#undef STAGE
  ushort_t* ob = out + (size_t)b*262144;
#pragma unroll
  for (int r = 0; r < 4; r++){
    const float rinv = 1.f / lacc[r];
    const size_t rowo = (size_t)(i0 + w*16 + q*4 + r)*256 + h*64 + l15;
#pragma unroll
    for (int nd = 0; nd < 4; nd++)
      ob[rowo + nd*16] = f2bfu(oacc[nd][r]*rinv);
  }
}

// ---------- host ----------
extern "C" void kernel_launch(void* const* d_in, const int* in_sizes, int n_in,
                              void* d_out, int out_size, void* d_ws, size_t ws_size,
                              hipStream_t stream)
{
  const float* x       = (const float*)d_in[0];
  const float* cv1_w   = (const float*)d_in[1];
  const float* cv1_bn  = (const float*)d_in[2];
  const float* cv2_w   = (const float*)d_in[3];
  const float* cv2_bn  = (const float*)d_in[4];
  const float* mcv1_w  = (const float*)d_in[5];
  const float* mcv1_bn = (const float*)d_in[6];
  const float* mqkv_w  = (const float*)d_in[7];
  const float* mrw     = (const float*)d_in[8];
  const float* mrh     = (const float*)d_in[9];
  const float* mcv2_w  = (const float*)d_in[10];
  const float* mcv2_bn = (const float*)d_in[11];

  ushort_t* uw = (ushort_t*)d_ws;
  ushort_t* x_cl    = uw;                  // 4,194,304
  ushort_t* t_cl    = x_cl    + 4194304;   // 4,194,304
  ushort_t* wb_cv1  = t_cl    + 4194304;   //   262,144
  ushort_t* wb_cv2  = wb_cv1  + 262144;    //   524,288
  ushort_t* wb_qkv  = wb_cv2  + 524288;    //   393,216
  ushort_t* wb_mcv2 = wb_qkv  + 393216;    //   131,072
  ushort_t* wb_mcv1 = wb_mcv2 + 131072;    // 1,179,648
  ushort_t* z1_cl   = wb_mcv1 + 1179648;   // 2,097,152
  ushort_t* qk_cl   = z1_cl   + 2097152;   // 4,194,304  [b][px][512]
  ushort_t* vt_b    = qk_cl   + 4194304;   // 2,097,152  [b][256][1024]
  ushort_t* att_cl  = vt_b    + 2097152;   // 2,097,152
  ushort_t* y2_cl   = att_cl  + 2097152;   // 2,097,152
  ushort_t* y3_cl   = y2_cl   + 2097152;   // 2,097,152
  float*    part_f  = (float*)(y3_cl + 2097152);  // 4,194,304 floats (16 MB)
  ushort_t* zbuf    = (ushort_t*)(part_f + 4194304); // 64 zeros

  const dim3 blk(256);

  prep_k<<<dim3(2560), blk, 0, stream>>>(x, x_cl,
      cv1_w, cv2_w, mqkv_w, mcv2_w, wb_cv1, wb_cv2, wb_qkv, wb_mcv2,
      mcv1_w, wb_mcv1, zbuf);

  // cv1: [512 co][512 ci] x x_cl -> t_cl (512 blocks)
  gemm_k<0,0,128><<<dim3(8,8,8), blk, 0, stream>>>(
      wb_cv1, 512, 512, 512, x_cl, nullptr, nullptr, nullptr, 512, 524288L,
      cv1_bn, nullptr, nullptr, nullptr, 0, 0, nullptr, nullptr, t_cl, 524288L, 512);

  const ushort_t* yi = t_cl + 256;  long yi_bs = 524288; int yi_rs = 512;
  ushort_t* youts[2] = { y2_cl, y3_cl };
  for (int i = 0; i < 2; i++){
    // conv3x3 implicit-im2col directly from yi, split-K x2 (512 blocks)
    gemm_k<2,4,128><<<dim3(4,8,16), blk, 0, stream>>>(
        wb_mcv1 + (size_t)i*589824, 256, 2304, 1152, yi, nullptr, nullptr, nullptr,
        yi_rs, yi_bs,
        nullptr, nullptr, nullptr, nullptr, 0, 0, nullptr, zbuf, part_f, 0, 0);
    reduce3_k<<<dim3(2048), blk, 0, stream>>>(part_f, mcv1_bn + i*1024, z1_cl);
    // qkv (768 blocks): q/k -> qk_cl [px][512], v -> vt_b NCHW
    gemm_k<0,1,128><<<dim3(12,8,8), blk, 0, stream>>>(
        wb_qkv + (size_t)i*196608, 768, 256, 256, z1_cl, nullptr, nullptr, nullptr, 256, 262144L,
        nullptr, mrw + i*8192, mrh + i*8192, nullptr, 0, 0, vt_b, nullptr, qk_cl, 524288L, 512);
    attn_k<<<dim3(16,4,8), blk, 0, stream>>>(qk_cl, vt_b, att_cl);
    // mcv2 + residual (512 blocks, 64x64 tile)
    gemm_k<0,2,64><<<dim3(4,16,8), blk, 0, stream>>>(
        wb_mcv2 + (size_t)i*65536, 256, 256, 256, att_cl, nullptr, nullptr, nullptr, 256, 262144L,
        mcv2_bn + i*1024, nullptr, nullptr, yi, yi_bs, yi_rs, nullptr, nullptr,
        youts[i], 262144L, 256);
    yi = youts[i]; yi_bs = 262144; yi_rs = 256;
  }

  // concat [y0|y1|y2|y3] 1024ch -> 512, fp32 NCHW out (512 blocks)
  gemm_k<1,3,128><<<dim3(8,8,8), blk, 0, stream>>>(
      wb_cv2, 512, 1024, 1024, t_cl, t_cl + 256, y2_cl, y3_cl, 0, 0,
      cv2_bn, nullptr, nullptr, nullptr, 0, 0, nullptr, nullptr, (float*)d_out, 524288L, 0);
}